// Round 16
// baseline (824.485 us; speedup 1.0000x reference)
//
#include <hip/hip_runtime.h>
#include <math.h>

#define PI2 6.283185307179586f

typedef short  bf16x8 __attribute__((ext_vector_type(8)));
typedef float  f32x4  __attribute__((ext_vector_type(4)));
typedef unsigned int u32x4 __attribute__((ext_vector_type(4)));
typedef unsigned int u32x2 __attribute__((ext_vector_type(2)));

__device__ __forceinline__ float gelu_exact(float x) {
    return 0.5f * x * (1.0f + erff(x * 0.70710678118654752f));
}
__device__ __forceinline__ float rcp_fast(float x) {
    float r;
    asm("v_rcp_f32 %0, %1" : "=v"(r) : "v"(x));
    return r;
}
// branch-free gelu: AS 7.1.26 erf (abs err 1.5e-7); raw v_rcp (arg>=1, ~1ulp)
__device__ __forceinline__ float gelu_fast(float x) {
    float ax = __builtin_fabsf(x);
    float s  = ax * 0.70710678118654752f;
    float t  = rcp_fast(fmaf(0.3275911f, s, 1.0f));
    float u  = fmaf(t, 1.061405429f, -1.453152027f);
    u = fmaf(t, u, 1.421413741f);
    u = fmaf(t, u, -0.284496736f);
    u = fmaf(t, u, 0.254829592f);
    float p  = t * u;
    float e  = __expf(-s * s);
    float q  = 0.5f * ax;
    return fmaf(-q * p, e, fmaf(0.5f, x, q));
}
__device__ __forceinline__ float bf2f(unsigned short u) {
    return __uint_as_float(((unsigned int)u) << 16);
}
__device__ __forceinline__ unsigned short f2bf(float f) {
    unsigned int b = __float_as_uint(f);
    unsigned int r = (b + 0x7FFFu + ((b >> 16) & 1u)) >> 16;   // RNE
    return (unsigned short)r;
}
__device__ __forceinline__ unsigned cvtpk_bf16(float lo, float hi) {
    unsigned r;
    asm("v_cvt_pk_bf16_f32 %0, %1, %2" : "=v"(r) : "v"(lo), "v"(hi));
    return r;
}
// result = lo16(a) | lo16(b)<<16  (1 inst)
__device__ __forceinline__ unsigned perm_lo(unsigned a, unsigned b) {
    unsigned r;
    asm("v_perm_b32 %0, %1, %2, %3" : "=v"(r) : "v"(b), "v"(a), "s"(0x05040100u));
    return r;
}
// result = hi16(a) | hi16(b)<<16  (1 inst)
__device__ __forceinline__ unsigned perm_hi(unsigned a, unsigned b) {
    unsigned r;
    asm("v_perm_b32 %0, %1, %2, %3" : "=v"(r) : "v"(b), "v"(a), "s"(0x07060302u));
    return r;
}

template<bool BF> struct HS;
template<> struct HS<false> {
    using ST = float;
    static __device__ __forceinline__ float4 ld4(const ST* p, size_t i4) {
        return reinterpret_cast<const float4*>(p)[i4];
    }
    static __device__ __forceinline__ void st4(ST* p, size_t i4, float4 v) {
        reinterpret_cast<float4*>(p)[i4] = v;
    }
};
template<> struct HS<true> {
    using ST = unsigned short;
    static __device__ __forceinline__ float4 ld4(const ST* p, size_t i4) {
        ushort4 u = reinterpret_cast<const ushort4*>(p)[i4];
        return make_float4(bf2f(u.x), bf2f(u.y), bf2f(u.z), bf2f(u.w));
    }
    static __device__ __forceinline__ void st4(ST* p, size_t i4, float4 v) {
        ushort4 u = make_ushort4(f2bf(v.x), f2bf(v.y), f2bf(v.z), f2bf(v.w));
        reinterpret_cast<ushort4*>(p)[i4] = u;
    }
};

// ============================ fallback-tier kernels =========================

template<bool BF>
__global__ void k_lift(const float* __restrict__ x, const float* __restrict__ lw,
                       const float* __restrict__ lb, typename HS<BF>::ST* __restrict__ h) {
    int i = blockIdx.x * 256 + threadIdx.x;
    int p4 = i & 16383;
    int bc = i >> 14;
    int c = bc & 63, b = bc >> 6;
    float4 xv = reinterpret_cast<const float4*>(x)[(size_t)b * 16384 + p4];
    float w = lw[c], bias = lb[c];
    float4 o;
    o.x = fmaf(xv.x, w, bias); o.y = fmaf(xv.y, w, bias);
    o.z = fmaf(xv.z, w, bias); o.w = fmaf(xv.w, w, bias);
    HS<BF>::st4(h, i, o);
}

template<bool BF>
__global__ __launch_bounds__(256) void k_coldft(const typename HS<BF>::ST* __restrict__ h,
                                                float2* __restrict__ Xw) {
    using ST = typename HS<BF>::ST;
    __shared__ __align__(16) ST xs[64 * 264];
    __shared__ __align__(16) float2 ct[12 * 258];
    int tid = threadIdx.x;
    size_t row0 = (size_t)blockIdx.x * 64;
#pragma unroll
    for (int k = 0; k < 12; k++) {
        int idx = tid + k * 256;
        int n = idx >> 8, w = idx & 255;
        int rr = (n * w) & 255;
        float s, c;
        __sincosf(PI2 * (float)rr * (1.0f / 256.0f), &s, &c);
        ct[n * 258 + w] = make_float2(c, -s);
    }
    const ST* src = h + row0 * 256;
    if constexpr (BF) {
#pragma unroll
        for (int k = 0; k < 8; k++) {
            int i = (tid + k * 256) * 8;
            int r = i >> 8, w = i & 255;
            uint4 v = *reinterpret_cast<const uint4*>(src + i);
            *reinterpret_cast<uint4*>(&xs[r * 264 + w]) = v;
        }
    } else {
#pragma unroll
        for (int k = 0; k < 16; k++) {
            int i = (tid + k * 256) * 4;
            int r = i >> 8, w = i & 255;
            float4 v = *reinterpret_cast<const float4*>(src + i);
            *reinterpret_cast<float4*>(&xs[r * 264 + w]) = v;
        }
    }
    __syncthreads();
    int r = tid >> 2, g = tid & 3;
    int n0 = g * 3;
    float a0r = 0.f, a0i = 0.f, a1r = 0.f, a1i = 0.f, a2r = 0.f, a2i = 0.f;
    const ST* xrow = &xs[r * 264];
    const float2* c0 = &ct[(n0 + 0) * 258];
    const float2* c1 = &ct[(n0 + 1) * 258];
    const float2* c2 = &ct[(n0 + 2) * 258];
#pragma unroll 8
    for (int wc = 0; wc < 256; wc += 4) {
        float x0, x1, x2, x3;
        if constexpr (BF) {
            ushort4 u = *reinterpret_cast<const ushort4*>(xrow + wc);
            x0 = bf2f(u.x); x1 = bf2f(u.y); x2 = bf2f(u.z); x3 = bf2f(u.w);
        } else {
            float4 f = *reinterpret_cast<const float4*>(xrow + wc);
            x0 = f.x; x1 = f.y; x2 = f.z; x3 = f.w;
        }
        float4 pa, pb;
        pa = *reinterpret_cast<const float4*>(c0 + wc);
        pb = *reinterpret_cast<const float4*>(c0 + wc + 2);
        a0r = fmaf(x0, pa.x, a0r); a0i = fmaf(x0, pa.y, a0i);
        a0r = fmaf(x1, pa.z, a0r); a0i = fmaf(x1, pa.w, a0i);
        a0r = fmaf(x2, pb.x, a0r); a0i = fmaf(x2, pb.y, a0i);
        a0r = fmaf(x3, pb.z, a0r); a0i = fmaf(x3, pb.w, a0i);
        pa = *reinterpret_cast<const float4*>(c1 + wc);
        pb = *reinterpret_cast<const float4*>(c1 + wc + 2);
        a1r = fmaf(x0, pa.x, a1r); a1i = fmaf(x0, pa.y, a1i);
        a1r = fmaf(x1, pa.z, a1r); a1i = fmaf(x1, pa.w, a1i);
        a1r = fmaf(x2, pb.x, a1r); a1i = fmaf(x2, pb.y, a1i);
        a1r = fmaf(x3, pb.z, a1r); a1i = fmaf(x3, pb.w, a1i);
        pa = *reinterpret_cast<const float4*>(c2 + wc);
        pb = *reinterpret_cast<const float4*>(c2 + wc + 2);
        a2r = fmaf(x0, pa.x, a2r); a2i = fmaf(x0, pa.y, a2i);
        a2r = fmaf(x1, pa.z, a2r); a2i = fmaf(x1, pa.w, a2i);
        a2r = fmaf(x2, pb.x, a2r); a2i = fmaf(x2, pb.y, a2i);
        a2r = fmaf(x3, pb.z, a2r); a2i = fmaf(x3, pb.w, a2i);
    }
    size_t bc = row0 >> 8;
    int hrow = (int)(row0 & 255) + r;
    float2* dst = Xw + (bc * 12) * 256 + hrow;
    dst[(size_t)(n0 + 0) * 256] = make_float2(a0r, a0i);
    dst[(size_t)(n0 + 1) * 256] = make_float2(a1r, a1i);
    dst[(size_t)(n0 + 2) * 256] = make_float2(a2r, a2i);
}

__global__ void k_rowdft(const float2* __restrict__ Xw, float2* __restrict__ F) {
    __shared__ float2 sm[12 * 257];
    int bc = blockIdx.x;
    const float2* src = Xw + (size_t)bc * 3072;
    for (int idx = threadIdx.x; idx < 3072; idx += 256) {
        int n = idx >> 8, hh = idx & 255;
        sm[n * 257 + hh] = src[idx];
    }
    __syncthreads();
    for (int j = threadIdx.x; j < 288; j += 256) {
        int n = j % 12, mm = j / 12;
        int meff = (mm < 12) ? mm : mm - 24;
        float s, c;
        __sincosf(-PI2 * (float)meff * (1.0f / 256.0f), &s, &c);
        float br = c, bi = s;
        float tr = 1.f, ti = 0.f, Fr = 0.f, Fi = 0.f;
        for (int hh = 0; hh < 256; hh++) {
            float2 xv = sm[n * 257 + hh];
            Fr = fmaf(xv.x, tr, Fr); Fr = fmaf(-xv.y, ti, Fr);
            Fi = fmaf(xv.x, ti, Fi); Fi = fmaf(xv.y, tr, Fi);
            float nr = tr * br - ti * bi;
            ti = tr * bi + ti * br;
            tr = nr;
        }
        F[(size_t)bc * 288 + j] = make_float2(Fr, Fi);
    }
}

__global__ void k_specmul(const float2* __restrict__ F,
                          const float* __restrict__ s1r, const float* __restrict__ s1i,
                          const float* __restrict__ s2r, const float* __restrict__ s2i,
                          float2* __restrict__ Y, int l) {
    __shared__ float2 wsh[4096];
    int mm = blockIdx.x / 12, n = blockIdx.x % 12;
    const float* wr; const float* wi; int m;
    if (mm < 12) { wr = s1r; wi = s1i; m = mm; }
    else         { wr = s2r; wi = s2i; m = mm - 12; }
    size_t base = (size_t)l * 589824 + (size_t)m * 12 + n;
    for (int idx = threadIdx.x; idx < 4096; idx += 256) {
        size_t a = base + (size_t)idx * 144;
        wsh[idx] = make_float2(wr[a], wi[a]);
    }
    __syncthreads();
    int o = threadIdx.x & 63, bq = threadIdx.x >> 6;
    for (int it = 0; it < 4; it++) {
        int b = bq * 4 + it;
        float Yr = 0.f, Yi = 0.f;
        const float2* Fb = F + (size_t)b * 64 * 288 + mm * 12 + n;
        for (int c = 0; c < 64; c++) {
            float2 fc = Fb[(size_t)c * 288];
            float2 wv = wsh[c * 64 + o];
            Yr = fmaf(fc.x, wv.x, Yr); Yr = fmaf(-fc.y, wv.y, Yr);
            Yi = fmaf(fc.x, wv.y, Yi); Yi = fmaf(fc.y, wv.x, Yi);
        }
        Y[((size_t)b * 64 + o) * 288 + mm * 12 + n] = make_float2(Yr, Yi);
    }
}

__global__ void k_expand(const float2* __restrict__ Y, float2* __restrict__ G) {
    int t = blockIdx.x * 256 + threadIdx.x;
    int hh = t & 255;
    int rem = t >> 8;
    int n = rem % 12, bo = rem / 12;
    const float2* Yb = Y + (size_t)bo * 288 + n;
    float s, c;
    __sincosf(PI2 * (float)hh * (1.0f / 256.0f), &s, &c);
    float br = c, bi = s;
    float tr = 1.f, ti = 0.f, Gr = 0.f, Gi = 0.f;
#pragma unroll
    for (int mm = 0; mm < 12; mm++) {
        float2 yv = Yb[mm * 12];
        Gr = fmaf(yv.x, tr, Gr); Gr = fmaf(-yv.y, ti, Gr);
        Gi = fmaf(yv.x, ti, Gi); Gi = fmaf(yv.y, tr, Gi);
        float nr = tr * br - ti * bi;
        ti = tr * bi + ti * br;
        tr = nr;
    }
    ti = -ti;
#pragma unroll
    for (int mm = 12; mm < 24; mm++) {
        float2 yv = Yb[mm * 12];
        Gr = fmaf(yv.x, tr, Gr); Gr = fmaf(-yv.y, ti, Gr);
        Gi = fmaf(yv.x, ti, Gi); Gi = fmaf(yv.y, tr, Gi);
        float nr = tr * br - ti * bi;
        ti = tr * bi + ti * br;
        tr = nr;
    }
    float sc = (n == 0 ? 1.0f : 2.0f) * (1.0f / 65536.0f);
    G[t] = make_float2(Gr * sc, Gi * sc);
}

template<bool BF>
__global__ __launch_bounds__(256) void k_update(
        typename HS<BF>::ST* __restrict__ h, const float2* __restrict__ G,
        const float* __restrict__ skw, const float* __restrict__ skb, int l) {
    __shared__ float hin[64 * 64];
    __shared__ float swT[64 * 68];
    __shared__ float2 Gs[64 * 12];
    __shared__ float2 ctab[12 * 64];
    int bx = blockIdx.x;
    int wt = bx & 3, hrow = (bx >> 2) & 255, b = bx >> 10;
    int w0 = wt * 64;
    int tid = threadIdx.x;
    size_t base4 = (size_t)b * 1048576 + (size_t)hrow * 64 + (w0 >> 2);
#pragma unroll
    for (int k = 0; k < 4; k++) {
        int idx = tid + k * 256;
        int c = idx >> 4, q = idx & 15;
        reinterpret_cast<float4*>(hin)[c * 16 + q] =
            HS<BF>::ld4(h, base4 + (size_t)c * 16384 + q);
    }
#pragma unroll
    for (int k = 0; k < 16; k++) {
        int idx = tid + k * 256;
        swT[(idx & 63) * 68 + (idx >> 6)] = skw[l * 4096 + idx];
    }
#pragma unroll
    for (int k = 0; k < 3; k++) {
        int idx = tid + k * 256;
        int o = idx / 12, n = idx % 12;
        Gs[idx] = G[(((size_t)b * 64 + o) * 12 + n) * 256 + hrow];
    }
#pragma unroll
    for (int k = 0; k < 3; k++) {
        int idx = tid + k * 256;
        int n = idx >> 6, wl = idx & 63;
        int r = (n * (w0 + wl)) & 255;
        float s, c;
        __sincosf(PI2 * (float)r * (1.0f / 256.0f), &s, &c);
        ctab[idx] = make_float2(c, s);
    }
    __syncthreads();
    int wq = tid & 15, oq = tid >> 4;
    float acc[4][4];
#pragma unroll
    for (int jo = 0; jo < 4; jo++) {
        float bias = skb[l * 64 + oq * 4 + jo];
#pragma unroll
        for (int jw = 0; jw < 4; jw++) acc[jo][jw] = bias;
    }
#pragma unroll
    for (int n = 0; n < 12; n++) {
        float2 g0 = Gs[(oq * 4 + 0) * 12 + n];
        float2 g1 = Gs[(oq * 4 + 1) * 12 + n];
        float2 g2 = Gs[(oq * 4 + 2) * 12 + n];
        float2 g3 = Gs[(oq * 4 + 3) * 12 + n];
#pragma unroll
        for (int jw = 0; jw < 4; jw++) {
            float2 cs = ctab[n * 64 + wq * 4 + jw];
            acc[0][jw] = fmaf(g0.x, cs.x, acc[0][jw]); acc[0][jw] = fmaf(-g0.y, cs.y, acc[0][jw]);
            acc[1][jw] = fmaf(g1.x, cs.x, acc[1][jw]); acc[1][jw] = fmaf(-g1.y, cs.y, acc[1][jw]);
            acc[2][jw] = fmaf(g2.x, cs.x, acc[2][jw]); acc[2][jw] = fmaf(-g2.y, cs.y, acc[2][jw]);
            acc[3][jw] = fmaf(g3.x, cs.x, acc[3][jw]); acc[3][jw] = fmaf(-g3.y, cs.y, acc[3][jw]);
        }
    }
    const float4* hin4 = reinterpret_cast<const float4*>(hin);
    const float4* swT4 = reinterpret_cast<const float4*>(swT);
#pragma unroll 4
    for (int c = 0; c < 64; c++) {
        float4 hv = hin4[c * 16 + wq];
        float4 wv = swT4[c * 17 + oq];
        acc[0][0] = fmaf(wv.x, hv.x, acc[0][0]); acc[0][1] = fmaf(wv.x, hv.y, acc[0][1]);
        acc[0][2] = fmaf(wv.x, hv.z, acc[0][2]); acc[0][3] = fmaf(wv.x, hv.w, acc[0][3]);
        acc[1][0] = fmaf(wv.y, hv.x, acc[1][0]); acc[1][1] = fmaf(wv.y, hv.y, acc[1][1]);
        acc[1][2] = fmaf(wv.y, hv.z, acc[1][2]); acc[1][3] = fmaf(wv.y, hv.w, acc[1][3]);
        acc[2][0] = fmaf(wv.z, hv.x, acc[2][0]); acc[2][1] = fmaf(wv.z, hv.y, acc[2][1]);
        acc[2][2] = fmaf(wv.z, hv.z, acc[2][2]); acc[2][3] = fmaf(wv.z, hv.w, acc[2][3]);
        acc[3][0] = fmaf(wv.w, hv.x, acc[3][0]); acc[3][1] = fmaf(wv.w, hv.y, acc[3][1]);
        acc[3][2] = fmaf(wv.w, hv.z, acc[3][2]); acc[3][3] = fmaf(wv.w, hv.w, acc[3][3]);
    }
#pragma unroll
    for (int jo = 0; jo < 4; jo++) {
        int o = oq * 4 + jo;
        float4 r;
        r.x = gelu_exact(acc[jo][0]); r.y = gelu_exact(acc[jo][1]);
        r.z = gelu_exact(acc[jo][2]); r.w = gelu_exact(acc[jo][3]);
        HS<BF>::st4(h, base4 + (size_t)o * 16384 + wq, r);
    }
}

template<bool BF>
__global__ void k_proj(const typename HS<BF>::ST* __restrict__ h, const float* __restrict__ pw,
                       const float* __restrict__ pb, float* __restrict__ out) {
    int i = blockIdx.x * 256 + threadIdx.x;
    int b = i >> 14, p4 = i & 16383;
    size_t hb = (size_t)b * 1048576 + p4;
    float4 acc = make_float4(0.f, 0.f, 0.f, 0.f);
#pragma unroll 8
    for (int c = 0; c < 64; c++) {
        float4 hv = HS<BF>::ld4(h, hb + (size_t)c * 16384);
        float wv = pw[c];
        acc.x = fmaf(hv.x, wv, acc.x); acc.y = fmaf(hv.y, wv, acc.y);
        acc.z = fmaf(hv.z, wv, acc.z); acc.w = fmaf(hv.w, wv, acc.w);
    }
    float bias = pb[0];
    acc.x += bias; acc.y += bias; acc.z += bias; acc.w += bias;
    reinterpret_cast<float4*>(out)[i] = acc;
}

// ============================ fused MFMA path (tier B) ======================
// G / Xw packed chunks (aliased buffer GXw, ushort): per (b,hrow) 3072 ushort:
//   [hi: 64 o x 24 k2][lo: 64 o x 24 k2], element (o, k2=2n+comp): o*24+n*2+comp
// Tg table (global ushort, 159,744 B): see R6 comment.
#define SKWHI 22528
#define SKWLO 38912
#define TW2US 55296
__global__ __launch_bounds__(256) void k_ttab(unsigned short* __restrict__ Tg,
                                              const float* __restrict__ skw) {
    int idx = blockIdx.x * 256 + threadIdx.x;     // 312*256 = 79872
    if (idx >= 79872) return;
    if (idx < 16384) {
        int q = idx & 8191;
        int w = q >> 5, b3 = (q >> 3) & 3;
        int k2 = ((b3 ^ (w & 3)) << 3) | (q & 7);
        float v = 0.f;
        if (k2 < 24) {
            int n = k2 >> 1, r = (n * w) & 255;
            float s, c;
            __sincosf(PI2 * (float)r * (1.0f / 256.0f), &s, &c);
            v = (k2 & 1) ? s : c;
        }
        if (idx < 8192) Tg[idx] = f2bf(v);
        else { unsigned short hi = f2bf(v); Tg[idx] = f2bf(v - bf2f(hi)); }
    } else if (idx < 22528) {
        int q = idx - 16384;
        int n2 = q >> 8, t = q & 255;
        int w = (((t >> 3) ^ (n2 & 7)) << 3) | (t & 7);
        int n = n2 >> 1, r = (n * w) & 255;
        float s, c;
        __sincosf(PI2 * (float)r * (1.0f / 256.0f), &s, &c);
        Tg[idx] = f2bf((n2 & 1) ? s : c);
    } else if (idx < 55296) {
        int q = idx - SKWHI;
        int lo = (q >= 16384);
        q &= 16383;
        float w = skw[q];
        unsigned short hi = f2bf(w);
        Tg[idx] = lo ? f2bf(w - bf2f(hi)) : hi;
    } else {
        int j = idx - TW2US;                      // 0..24575, one float each
        int pair = j >> 1, comp = j & 1;
        int mm = pair >> 8, hh = pair & 255;
        int meff = (mm < 12) ? mm : mm - 24;
        int r = (((-(meff * hh)) % 256) + 256) & 255;
        float s, c;
        __sincosf(PI2 * (float)r * (1.0f / 256.0f), &s, &c);
        reinterpret_cast<float*>(Tg + TW2US)[j] = comp ? s : c;
    }
}

// layer-0 Xw chunks via the rank-1 lift identity
__global__ __launch_bounds__(256) void k_xw0(const float* __restrict__ xg,
                                             const float* __restrict__ lw,
                                             const float* __restrict__ lb,
                                             unsigned short* __restrict__ Xwp) {
    __shared__ float xr[256];
    __shared__ float part[24][9];
    __shared__ float xh[24];
    int blk = blockIdx.x;                         // b*256 + hrow
    int tid = threadIdx.x;
    if (tid < 64)
        reinterpret_cast<float4*>(xr)[tid] =
            reinterpret_cast<const float4*>(xg + (size_t)blk * 256)[tid];
    __syncthreads();
    if (tid < 192) {
        int n2 = tid % 24, seg = tid / 24;
        int n = n2 >> 1, comp = n2 & 1;
        float acc = 0.f;
#pragma unroll 8
        for (int j = 0; j < 32; j++) {
            int w = seg * 32 + j;
            int r = (n * w) & 255;
            float s, c;
            __sincosf(PI2 * (float)r * (1.0f / 256.0f), &s, &c);
            acc = fmaf(xr[w], comp ? -s : c, acc);
        }
        part[n2][seg] = acc;
    }
    __syncthreads();
    if (tid < 24) {
        float a = 0.f;
#pragma unroll
        for (int s = 0; s < 8; s++) a += part[tid][s];
        xh[tid] = a;
    }
    __syncthreads();
    unsigned* dstw = reinterpret_cast<unsigned*>(Xwp + (size_t)blk * 3072);
#pragma unroll
    for (int q = 0; q < 3; q++) {
        int i = tid + q * 256;
        int c = i / 12, n = i % 12;
        float wr = lw[c];
        float re = fmaf(wr, xh[2 * n], (n == 0) ? lb[c] * 256.0f : 0.0f);
        float im = wr * xh[2 * n + 1];
        unsigned short hre = f2bf(re), him = f2bf(im);
        unsigned short lre = f2bf(re - bf2f(hre)), lim = f2bf(im - bf2f(him));
        dstw[i] = (unsigned)hre | ((unsigned)him << 16);
        dstw[768 + i] = (unsigned)lre | ((unsigned)lim << 16);
    }
}

// row DFT reading packed Xw chunks — b128 vectorized, 2 accumulator pairs
__global__ __launch_bounds__(256) void k_rowdft2t(const unsigned short* __restrict__ Xwp,
                                                  float2* __restrict__ F,
                                                  const float2* __restrict__ tw2) {
    __shared__ __align__(16) float2 sm[12 * 258];
    int bc = blockIdx.x;
    int b = bc >> 6, c = bc & 63;
    for (int idx = threadIdx.x; idx < 3072; idx += 256) {
        int hh = idx / 12, n = idx % 12;
        size_t base = ((size_t)(b * 256 + hh)) * 3072 + c * 24 + n * 2;
        unsigned hi = *reinterpret_cast<const unsigned*>(Xwp + base);
        unsigned lo = *reinterpret_cast<const unsigned*>(Xwp + base + 1536);
        float re = bf2f((unsigned short)(hi & 0xffff)) + bf2f((unsigned short)(lo & 0xffff));
        float im = bf2f((unsigned short)(hi >> 16)) + bf2f((unsigned short)(lo >> 16));
        sm[n * 258 + hh] = make_float2(re, im);
    }
    __syncthreads();
    for (int j = threadIdx.x; j < 288; j += 256) {
        int n = j % 12, mm = j / 12;
        const float4* twp = reinterpret_cast<const float4*>(tw2 + mm * 256);
        const float4* smp = reinterpret_cast<const float4*>(&sm[n * 258]);
        float Fr0 = 0.f, Fi0 = 0.f, Fr1 = 0.f, Fi1 = 0.f;
#pragma unroll 8
        for (int p = 0; p < 128; p++) {
            float4 xv = smp[p];                   // 2 complex samples
            float4 wv = twp[p];
            Fr0 = fmaf(xv.x, wv.x, Fr0); Fr0 = fmaf(-xv.y, wv.y, Fr0);
            Fi0 = fmaf(xv.x, wv.y, Fi0); Fi0 = fmaf(xv.y, wv.x, Fi0);
            Fr1 = fmaf(xv.z, wv.z, Fr1); Fr1 = fmaf(-xv.w, wv.w, Fr1);
            Fi1 = fmaf(xv.z, wv.w, Fi1); Fi1 = fmaf(xv.w, wv.z, Fi1);
        }
        F[(size_t)bc * 288 + j] = make_float2(Fr0 + Fr1, Fi0 + Fi1);
    }
}

// specmul, high-MLP version: 1024 threads, b folded into the thread grid
__global__ __launch_bounds__(1024) void k_specmul2(const float2* __restrict__ F,
                          const float* __restrict__ s1r, const float* __restrict__ s1i,
                          const float* __restrict__ s2r, const float* __restrict__ s2i,
                          float2* __restrict__ Y, int l) {
    __shared__ float2 wsh[4096];
    __shared__ float2 fsh[1024];
    int mm = blockIdx.x / 12, n = blockIdx.x % 12;
    const float* wr; const float* wi; int m;
    if (mm < 12) { wr = s1r; wi = s1i; m = mm; }
    else         { wr = s2r; wi = s2i; m = mm - 12; }
    size_t base = (size_t)l * 589824 + (size_t)m * 12 + n;
    int tid = threadIdx.x;
#pragma unroll
    for (int k = 0; k < 4; k++) {
        int idx = tid + k * 1024;                 // idx = c*64+o
        size_t a = base + (size_t)idx * 144;
        wsh[idx] = make_float2(wr[a], wi[a]);
    }
    fsh[tid] = F[(size_t)tid * 288 + mm * 12 + n];  // tid = b*64+c
    __syncthreads();
    int o = tid & 63, b = tid >> 6;
    const float2* fb = &fsh[b * 64];
    float Yr = 0.f, Yi = 0.f;
#pragma unroll 8
    for (int c = 0; c < 64; c++) {
        float2 fc = fb[c];
        float2 wv = wsh[c * 64 + o];
        Yr = fmaf(fc.x, wv.x, Yr); Yr = fmaf(-fc.y, wv.y, Yr);
        Yi = fmaf(fc.x, wv.y, Yi); Yi = fmaf(fc.y, wv.x, Yi);
    }
    Y[((size_t)(b * 64 + o)) * 288 + mm * 12 + n] = make_float2(Yr, Yi);
}

// expand writing packed G chunks (re, -im) hi/lo, block = (b, hh)
__global__ __launch_bounds__(256) void k_expand2(const float2* __restrict__ Y,
                                                 unsigned short* __restrict__ Gpk) {
    __shared__ float2 tw[24];
    int blk = blockIdx.x;
    int hh = blk & 255, b = blk >> 8;
    int t = threadIdx.x;
    if (t < 24) {
        int meff = (t < 12) ? t : t - 24;
        int r = (meff * hh) & 255;
        float s, c;
        __sincosf(PI2 * (float)r * (1.0f / 256.0f), &s, &c);
        tw[t] = make_float2(c, s);
    }
    __syncthreads();
    const float2* Yb = Y + (size_t)b * 64 * 288;
    unsigned short* Gb = Gpk + ((size_t)(b * 256 + hh)) * 3072;
#pragma unroll
    for (int q = 0; q < 3; q++) {
        int i = t * 3 + q;
        int o = i / 12, n = i % 12;
        const float2* Yp = Yb + o * 288 + n;
        float Gr = 0.f, Gi = 0.f;
#pragma unroll
        for (int mm = 0; mm < 24; mm++) {
            float2 yv = Yp[mm * 12];
            float2 w = tw[mm];
            Gr = fmaf(yv.x, w.x, Gr); Gr = fmaf(-yv.y, w.y, Gr);
            Gi = fmaf(yv.x, w.y, Gi); Gi = fmaf(yv.y, w.x, Gi);
        }
        float sc = (n == 0 ? 1.0f : 2.0f) * (1.0f / 65536.0f);
        float gr = Gr * sc, gi = -Gi * sc;
        unsigned short hre = f2bf(gr), him = f2bf(gi);
        unsigned short lre = f2bf(gr - bf2f(hre)), lim = f2bf(gi - bf2f(him));
        int off = o * 24 + n * 2;
        *reinterpret_cast<unsigned*>(Gb + off) = (unsigned)hre | ((unsigned)him << 16);
        *reinterpret_cast<unsigned*>(Gb + 1536 + off) = (unsigned)lre | ((unsigned)lim << 16);
    }
}

// fused: transposed GEMM (D=[w][o]) + gelu + {h write | proj} + {colDFT | -}.
// 512 threads = 8 waves: wave (ww=wid>>2, wo=wid&3) owns w-half ww, o-16 wo.
// hnew is XOR-swizzled [64][256] in the hT region (32 KB total LDS).
// colDFT is split across w-halves; partials combined via LDS f32 region.
template<bool FIRST, bool LAST>
__global__ __launch_bounds__(512, 4) void k_fused3(
        unsigned short* hg, const float* __restrict__ xg,
        const float* __restrict__ lw, const float* __restrict__ lb,
        unsigned short* GXw, const float* __restrict__ skb,
        const float* __restrict__ pw, const float* __restrict__ pb,
        float* __restrict__ outg, const unsigned short* __restrict__ Tg, int l) {
    __shared__ __align__(16) unsigned short lds[16384];   // hT | hnew (swizzled)
    int tid = threadIdx.x, lane = tid & 63, wid = tid >> 6;
    int lr = lane & 15, lg = lane >> 4;
    int ww = wid >> 2, wo = wid & 3;
    int bx = blockIdx.x;
    int hrow = bx & 255, b = bx >> 8;

    // ---- stage hT[w][c] (swizzled) ----
    if constexpr (FIRST) {
#pragma unroll
        for (int k = 0; k < 2; k++) {
            int pidx = tid + k * 512;
            int cp = pidx >> 5, w0 = (pidx & 31) * 8;
            int c0 = cp * 2;
            float wa = lw[c0], ba = lb[c0];
            float wb = lw[c0 + 1], bb = lb[c0 + 1];
            float4 xv0 = *reinterpret_cast<const float4*>(xg + (size_t)bx * 256 + w0);
            float4 xv1 = *reinterpret_cast<const float4*>(xg + (size_t)bx * 256 + w0 + 4);
            float xv[8] = {xv0.x, xv0.y, xv0.z, xv0.w, xv1.x, xv1.y, xv1.z, xv1.w};
            int sl = (c0 >> 3) & 7, cl = c0 & 7;
#pragma unroll
            for (int j = 0; j < 8; j++) {
                int w = w0 + j;
                float h0 = fmaf(xv[j], wa, ba);
                float h1 = fmaf(xv[j], wb, bb);
                int Xws = (w & 7) ^ ((w >> 3) & 7);
                *reinterpret_cast<unsigned*>(&lds[w * 64 + (((sl ^ Xws) & 7) << 3) + cl]) =
                    cvtpk_bf16(h0, h1);
            }
        }
    } else {
        // c-quad staging: 512 items; b64 LDS writes (2-way bank = free)
        {
            int item = tid;
            int q = item >> 5, w0 = (item & 31) * 8;
            int c0 = q * 4;
            const unsigned short* s0 = hg + ((size_t)(b * 64 + c0) * 256 + hrow) * 256 + w0;
            uint4 v0 = *reinterpret_cast<const uint4*>(s0);
            uint4 v1 = *reinterpret_cast<const uint4*>(s0 + 65536);
            uint4 v2 = *reinterpret_cast<const uint4*>(s0 + 131072);
            uint4 v3 = *reinterpret_cast<const uint4*>(s0 + 196608);
            unsigned a01[8], a23[8];
            a01[0] = perm_lo(v0.x, v1.x); a01[1] = perm_hi(v0.x, v1.x);
            a01[2] = perm_lo(v0.y, v1.y); a01[3] = perm_hi(v0.y, v1.y);
            a01[4] = perm_lo(v0.z, v1.z); a01[5] = perm_hi(v0.z, v1.z);
            a01[6] = perm_lo(v0.w, v1.w); a01[7] = perm_hi(v0.w, v1.w);
            a23[0] = perm_lo(v2.x, v3.x); a23[1] = perm_hi(v2.x, v3.x);
            a23[2] = perm_lo(v2.y, v3.y); a23[3] = perm_hi(v2.y, v3.y);
            a23[4] = perm_lo(v2.z, v3.z); a23[5] = perm_hi(v2.z, v3.z);
            a23[6] = perm_lo(v2.w, v3.w); a23[7] = perm_hi(v2.w, v3.w);
            int sl = (c0 >> 3) & 7, cl = c0 & 7;   // cl in {0,4}
#pragma unroll
            for (int j = 0; j < 8; j++) {
                int w = w0 + j;
                int Xws = (w & 7) ^ ((w >> 3) & 7);
                u32x2 pk;
                pk[0] = a01[j]; pk[1] = a23[j];
                *reinterpret_cast<u32x2*>(&lds[w * 64 + (((sl ^ Xws) & 7) << 3) + cl]) = pk;
            }
        }
    }
    // ---- B fragments: skw hi/lo + G hi/lo, col o = wo*16+lr ----
    int oA = wo * 16 + lr;
    bf16x8 bs_h[2], bs_l[2];
#pragma unroll
    for (int ks = 0; ks < 2; ks++) {
        int off = l * 4096 + oA * 64 + ks * 32 + lg * 8;
        bs_h[ks] = __builtin_bit_cast(bf16x8,
            *reinterpret_cast<const u32x4*>(Tg + SKWHI + off));
        bs_l[ks] = __builtin_bit_cast(bf16x8,
            *reinterpret_cast<const u32x4*>(Tg + SKWLO + off));
    }
    int lgc = (lg < 3) ? lg : 2;
    size_t gbase = ((size_t)(b * 256 + hrow)) * 3072 + (size_t)oA * 24 + lgc * 8;
    u32x4 ghv = *reinterpret_cast<const u32x4*>(GXw + gbase);
    u32x4 glv = *reinterpret_cast<const u32x4*>(GXw + gbase + 1536);
    if (lg == 3) { ghv = (u32x4){0, 0, 0, 0}; glv = (u32x4){0, 0, 0, 0}; }
    bf16x8 bg_h = __builtin_bit_cast(bf16x8, ghv);
    bf16x8 bg_l = __builtin_bit_cast(bf16x8, glv);
    float bias_o = skb[l * 64 + oA];
    f32x4 binit = {bias_o, bias_o, bias_o, bias_o};

    __syncthreads();

    // ---- main GEMM (operand-swapped): acc[wt] = D'[w][o], w-half ww ----
    f32x4 acc[8];
#pragma unroll
    for (int wt = 0; wt < 8; wt++) acc[wt] = binit;
    __builtin_amdgcn_s_setprio(1);
#pragma unroll
    for (int wt = 0; wt < 8; wt++) {
        int w = ww * 128 + wt * 16 + lr;
        int Xws = (w & 7) ^ ((w >> 3) & 7);
        int i0 = w * 64 + (((lg ^ Xws) & 7) << 3);
        int i1 = w * 64 + ((((4 + lg) ^ Xws) & 7) << 3);
        int it = w * 32 + (((lg ^ (w & 3)) & 3) << 3);
        bf16x8 A0 = __builtin_bit_cast(bf16x8, *reinterpret_cast<const u32x4*>(&lds[i0]));
        bf16x8 A1 = __builtin_bit_cast(bf16x8, *reinterpret_cast<const u32x4*>(&lds[i1]));
        bf16x8 Th = __builtin_bit_cast(bf16x8, *reinterpret_cast<const u32x4*>(Tg + it));
        bf16x8 Tl = __builtin_bit_cast(bf16x8, *reinterpret_cast<const u32x4*>(Tg + 8192 + it));
        acc[wt] = __builtin_amdgcn_mfma_f32_16x16x32_bf16(A0, bs_h[0], acc[wt], 0, 0, 0);
        acc[wt] = __builtin_amdgcn_mfma_f32_16x16x32_bf16(A0, bs_l[0], acc[wt], 0, 0, 0);
        acc[wt] = __builtin_amdgcn_mfma_f32_16x16x32_bf16(A1, bs_h[1], acc[wt], 0, 0, 0);
        acc[wt] = __builtin_amdgcn_mfma_f32_16x16x32_bf16(A1, bs_l[1], acc[wt], 0, 0, 0);
        acc[wt] = __builtin_amdgcn_mfma_f32_16x16x32_bf16(Th, bg_h, acc[wt], 0, 0, 0);
        acc[wt] = __builtin_amdgcn_mfma_f32_16x16x32_bf16(Tl, bg_h, acc[wt], 0, 0, 0);
        acc[wt] = __builtin_amdgcn_mfma_f32_16x16x32_bf16(Th, bg_l, acc[wt], 0, 0, 0);
    }
    __builtin_amdgcn_s_setprio(0);
    __syncthreads();                              // hT dead

    // ---- epilogue: gelu + cvt_pk -> swizzled hnew (b64 writes) ----
    int wD = lg * 4;
    int osw = (oA & 7) << 3;
#pragma unroll
    for (int wt = 0; wt < 8; wt++) {
        float v0 = gelu_fast(acc[wt][0]);
        float v1 = gelu_fast(acc[wt][1]);
        float v2 = gelu_fast(acc[wt][2]);
        float v3 = gelu_fast(acc[wt][3]);
        u32x2 pk;
        pk[0] = cvtpk_bf16(v0, v1);
        pk[1] = cvtpk_bf16(v2, v3);
        *reinterpret_cast<u32x2*>(&lds[oA * 256 + ((ww * 128 + wt * 16 + wD) ^ osw)]) = pk;
    }
    __syncthreads();

    if constexpr (LAST) {
        // ---- proj-reduce: out[b,hrow,w] = pb + sum_o pw[o]*hnew[o][w] ----
        if (tid < 256) {
            float accp = pb[0];
#pragma unroll 8
            for (int o = 0; o < 64; o++)
                accp = fmaf(pw[o], bf2f(lds[o * 256 + (tid ^ ((o & 7) << 3))]), accp);
            outg[(size_t)bx * 256 + tid] = accp;
        }
        return;
    }

    // ---- copy hnew -> global (coalesced; swizzled b128 LDS reads) ----
#pragma unroll
    for (int k = 0; k < 4; k++) {
        int chi = k * 512 + tid;
        int o = chi >> 5, wq = (chi & 31) * 8;
        u32x4 v = *reinterpret_cast<const u32x4*>(&lds[o * 256 + (wq ^ ((o & 7) << 3))]);
        *reinterpret_cast<u32x4*>(hg + ((size_t)(b * 64 + o) * 256 + hrow) * 256 + wq) = v;
    }
    // ---- fused column-DFT for next layer (partial over w-half ww) ----
    f32x4 acc2[2];
    acc2[0] = (f32x4){0.f, 0.f, 0.f, 0.f};
    acc2[1] = (f32x4){0.f, 0.f, 0.f, 0.f};
    int oa = wo * 16 + lr;
    int oasw = (oa & 7) << 3;
#pragma unroll
    for (int sg = 0; sg < 4; sg++) {
        int wb = ww * 16 + 4 * sg + lg;
        bf16x8 Af = __builtin_bit_cast(bf16x8,
            *reinterpret_cast<const u32x4*>(&lds[oa * 256 + ((wb * 8) ^ oasw)]));
#pragma unroll
        for (int nt = 0; nt < 2; nt++) {
            int n2 = nt * 16 + lr;
            int n2r = (n2 < 24) ? n2 : 23;        // cols >=24 discarded
            bf16x8 Bf = __builtin_bit_cast(bf16x8, *reinterpret_cast<const u32x4*>(
                Tg + 16384 + n2r * 256 + ((wb ^ (n2r & 7)) << 3)));
            acc2[nt] = __builtin_amdgcn_mfma_f32_16x16x32_bf16(Af, Bf, acc2[nt], 0, 0, 0);
        }
    }
    __syncthreads();                              // hnew LDS dead
    // ---- combine w-half partials via LDS f32 region, then pack Xw ----
    float* fp = reinterpret_cast<float*>(lds);    // [2][64][24] f32 = 12,288 B
    int oD = wo * 16 + lg * 4;
#pragma unroll
    for (int nt = 0; nt < 2; nt++) {
        int n2 = nt * 16 + lr;
        if (n2 < 24) {
#pragma unroll
            for (int r = 0; r < 4; r++)
                fp[ww * 1536 + (oD + r) * 24 + n2] = acc2[nt][r];
        }
    }
    __syncthreads();
    // pack: 1536 (o,n2) values, 256 threads x 6 each -> chunk at lds16[8192..]
    if (tid < 256) {
#pragma unroll
        for (int e = 0; e < 6; e++) {
            int idx = tid * 6 + e;
            int o = idx / 24, n2 = idx % 24;
            float v = fp[idx] + fp[1536 + idx];
            if (n2 & 1) v = -v;
            unsigned short hv = f2bf(v);
            unsigned short lv = f2bf(v - bf2f(hv));
            lds[8192 + o * 24 + n2] = hv;
            lds[8192 + 1536 + o * 24 + n2] = lv;
        }
    }
    __syncthreads();
    unsigned* dstw = reinterpret_cast<unsigned*>(GXw + ((size_t)(b * 256 + hrow)) * 3072);
    const unsigned* srcw = reinterpret_cast<const unsigned*>(lds) + 4096;
#pragma unroll
    for (int k = 0; k < 2; k++) {
        int i = tid + k * 512;                    // 768 u32
        if (i < 768) dstw[i] = srcw[i];
    }
}

// ============================ dispatch ======================================

template<bool BF>
static void run_pipeline_old(void* const* d_in, void* d_out, void* d_ws, hipStream_t stream) {
    const float* x   = (const float*)d_in[0];
    const float* lw  = (const float*)d_in[1];
    const float* lb  = (const float*)d_in[2];
    const float* s1r = (const float*)d_in[3];
    const float* s1i = (const float*)d_in[4];
    const float* s2r = (const float*)d_in[5];
    const float* s2i = (const float*)d_in[6];
    const float* skw = (const float*)d_in[7];
    const float* skb = (const float*)d_in[8];
    const float* pw  = (const float*)d_in[9];
    const float* pb  = (const float*)d_in[10];
    float* out = (float*)d_out;
    char* ws = (char*)d_ws;
    using ST = typename HS<BF>::ST;
    size_t hbytes = 67108864ull * sizeof(ST);
    ST*     hbuf = (ST*)ws;
    float2* XwG  = (float2*)(ws + hbytes);
    float2* F    = (float2*)(ws + hbytes + 25165824ull);
    float2* Y    = (float2*)(ws + hbytes + 25165824ull + 2359296ull);
    k_lift<BF><<<65536, 256, 0, stream>>>(x, lw, lb, hbuf);
    for (int l = 0; l < 4; l++) {
        k_coldft<BF><<<4096, 256, 0, stream>>>(hbuf, XwG);
        k_rowdft <<<1024,  256, 0, stream>>>(XwG, F);
        k_specmul<<<288,   256, 0, stream>>>(F, s1r, s1i, s2r, s2i, Y, l);
        k_expand <<<12288, 256, 0, stream>>>(Y, XwG);
        k_update<BF><<<16384, 256, 0, stream>>>(hbuf, XwG, skw, skb, l);
    }
    k_proj<BF><<<1024, 256, 0, stream>>>(hbuf, pw, pb, out);
}

static void run_pipeline_fused(void* const* d_in, void* d_out, void* d_ws, hipStream_t stream) {
    const float* x   = (const float*)d_in[0];
    const float* lw  = (const float*)d_in[1];
    const float* lb  = (const float*)d_in[2];
    const float* s1r = (const float*)d_in[3];
    const float* s1i = (const float*)d_in[4];
    const float* s2r = (const float*)d_in[5];
    const float* s2i = (const float*)d_in[6];
    const float* skw = (const float*)d_in[7];
    const float* skb = (const float*)d_in[8];
    const float* pw  = (const float*)d_in[9];
    const float* pb  = (const float*)d_in[10];
    float* out = (float*)d_out;
    char* ws = (char*)d_ws;
    unsigned short* hbuf = (unsigned short*)ws;
    unsigned short* XwG  = (unsigned short*)(ws + 134217728ull);
    float2* F   = (float2*)(ws + 134217728ull + 25165824ull);
    float2* Y   = (float2*)(ws + 134217728ull + 25165824ull + 2359296ull);
    unsigned short* Tg = (unsigned short*)(ws + 164102144ull);
    const float2* tw2 = (const float2*)((char*)Tg + 110592);

    k_ttab<<<312, 256, 0, stream>>>(Tg, skw);
    k_xw0<<<4096, 256, 0, stream>>>(x, lw, lb, XwG);
    for (int l = 0; l < 4; l++) {
        k_rowdft2t<<<1024, 256, 0, stream>>>(XwG, F, tw2);
        k_specmul2<<<288, 1024, 0, stream>>>(F, s1r, s1i, s2r, s2i, Y, l);
        k_expand2<<<4096, 256, 0, stream>>>(Y, XwG);
        if (l == 0)
            k_fused3<true, false><<<4096, 512, 0, stream>>>(hbuf, x, lw, lb, XwG, skb, pw, pb, out, Tg, l);
        else if (l == 3)
            k_fused3<false, true><<<4096, 512, 0, stream>>>(hbuf, x, lw, lb, XwG, skb, pw, pb, out, Tg, l);
        else
            k_fused3<false, false><<<4096, 512, 0, stream>>>(hbuf, x, lw, lb, XwG, skb, pw, pb, out, Tg, l);
    }
}

extern "C" void kernel_launch(void* const* d_in, const int* in_sizes, int n_in,
                              void* d_out, int out_size, void* d_ws, size_t ws_size,
                              hipStream_t stream) {
    // fused tier: 164,102,144 (bf16 h + XwG + F + Y) + 159,744 (Tg) = 164,261,888
    if (ws_size >= 164261888ull) {
        run_pipeline_fused(d_in, d_out, d_ws, stream);
    } else {
        run_pipeline_old<true>(d_in, d_out, d_ws, stream);
    }
}

// Round 17
// 776.540 us; speedup vs baseline: 1.0617x; 1.0617x over previous
//
#include <hip/hip_runtime.h>
#include <math.h>

#define PI2 6.283185307179586f

typedef short  bf16x8 __attribute__((ext_vector_type(8)));
typedef float  f32x4  __attribute__((ext_vector_type(4)));
typedef unsigned int u32x4 __attribute__((ext_vector_type(4)));
typedef unsigned int u32x2 __attribute__((ext_vector_type(2)));

__device__ __forceinline__ float gelu_exact(float x) {
    return 0.5f * x * (1.0f + erff(x * 0.70710678118654752f));
}
__device__ __forceinline__ float rcp_fast(float x) {
    float r;
    asm("v_rcp_f32 %0, %1" : "=v"(r) : "v"(x));
    return r;
}
// branch-free gelu: AS 7.1.26 erf (abs err 1.5e-7); raw v_rcp (arg>=1, ~1ulp)
__device__ __forceinline__ float gelu_fast(float x) {
    float ax = __builtin_fabsf(x);
    float s  = ax * 0.70710678118654752f;
    float t  = rcp_fast(fmaf(0.3275911f, s, 1.0f));
    float u  = fmaf(t, 1.061405429f, -1.453152027f);
    u = fmaf(t, u, 1.421413741f);
    u = fmaf(t, u, -0.284496736f);
    u = fmaf(t, u, 0.254829592f);
    float p  = t * u;
    float e  = __expf(-s * s);
    float q  = 0.5f * ax;
    return fmaf(-q * p, e, fmaf(0.5f, x, q));
}
__device__ __forceinline__ float bf2f(unsigned short u) {
    return __uint_as_float(((unsigned int)u) << 16);
}
__device__ __forceinline__ unsigned short f2bf(float f) {
    unsigned int b = __float_as_uint(f);
    unsigned int r = (b + 0x7FFFu + ((b >> 16) & 1u)) >> 16;   // RNE
    return (unsigned short)r;
}
__device__ __forceinline__ unsigned cvtpk_bf16(float lo, float hi) {
    unsigned r;
    asm("v_cvt_pk_bf16_f32 %0, %1, %2" : "=v"(r) : "v"(lo), "v"(hi));
    return r;
}
// result = lo16(a) | lo16(b)<<16  (1 inst)
__device__ __forceinline__ unsigned perm_lo(unsigned a, unsigned b) {
    unsigned r;
    asm("v_perm_b32 %0, %1, %2, %3" : "=v"(r) : "v"(b), "v"(a), "s"(0x05040100u));
    return r;
}
// result = hi16(a) | hi16(b)<<16  (1 inst)
__device__ __forceinline__ unsigned perm_hi(unsigned a, unsigned b) {
    unsigned r;
    asm("v_perm_b32 %0, %1, %2, %3" : "=v"(r) : "v"(b), "v"(a), "s"(0x07060302u));
    return r;
}

template<bool BF> struct HS;
template<> struct HS<false> {
    using ST = float;
    static __device__ __forceinline__ float4 ld4(const ST* p, size_t i4) {
        return reinterpret_cast<const float4*>(p)[i4];
    }
    static __device__ __forceinline__ void st4(ST* p, size_t i4, float4 v) {
        reinterpret_cast<float4*>(p)[i4] = v;
    }
};
template<> struct HS<true> {
    using ST = unsigned short;
    static __device__ __forceinline__ float4 ld4(const ST* p, size_t i4) {
        ushort4 u = reinterpret_cast<const ushort4*>(p)[i4];
        return make_float4(bf2f(u.x), bf2f(u.y), bf2f(u.z), bf2f(u.w));
    }
    static __device__ __forceinline__ void st4(ST* p, size_t i4, float4 v) {
        ushort4 u = make_ushort4(f2bf(v.x), f2bf(v.y), f2bf(v.z), f2bf(v.w));
        reinterpret_cast<ushort4*>(p)[i4] = u;
    }
};

// ============================ fallback-tier kernels =========================

template<bool BF>
__global__ void k_lift(const float* __restrict__ x, const float* __restrict__ lw,
                       const float* __restrict__ lb, typename HS<BF>::ST* __restrict__ h) {
    int i = blockIdx.x * 256 + threadIdx.x;
    int p4 = i & 16383;
    int bc = i >> 14;
    int c = bc & 63, b = bc >> 6;
    float4 xv = reinterpret_cast<const float4*>(x)[(size_t)b * 16384 + p4];
    float w = lw[c], bias = lb[c];
    float4 o;
    o.x = fmaf(xv.x, w, bias); o.y = fmaf(xv.y, w, bias);
    o.z = fmaf(xv.z, w, bias); o.w = fmaf(xv.w, w, bias);
    HS<BF>::st4(h, i, o);
}

template<bool BF>
__global__ __launch_bounds__(256) void k_coldft(const typename HS<BF>::ST* __restrict__ h,
                                                float2* __restrict__ Xw) {
    using ST = typename HS<BF>::ST;
    __shared__ __align__(16) ST xs[64 * 264];
    __shared__ __align__(16) float2 ct[12 * 258];
    int tid = threadIdx.x;
    size_t row0 = (size_t)blockIdx.x * 64;
#pragma unroll
    for (int k = 0; k < 12; k++) {
        int idx = tid + k * 256;
        int n = idx >> 8, w = idx & 255;
        int rr = (n * w) & 255;
        float s, c;
        __sincosf(PI2 * (float)rr * (1.0f / 256.0f), &s, &c);
        ct[n * 258 + w] = make_float2(c, -s);
    }
    const ST* src = h + row0 * 256;
    if constexpr (BF) {
#pragma unroll
        for (int k = 0; k < 8; k++) {
            int i = (tid + k * 256) * 8;
            int r = i >> 8, w = i & 255;
            uint4 v = *reinterpret_cast<const uint4*>(src + i);
            *reinterpret_cast<uint4*>(&xs[r * 264 + w]) = v;
        }
    } else {
#pragma unroll
        for (int k = 0; k < 16; k++) {
            int i = (tid + k * 256) * 4;
            int r = i >> 8, w = i & 255;
            float4 v = *reinterpret_cast<const float4*>(src + i);
            *reinterpret_cast<float4*>(&xs[r * 264 + w]) = v;
        }
    }
    __syncthreads();
    int r = tid >> 2, g = tid & 3;
    int n0 = g * 3;
    float a0r = 0.f, a0i = 0.f, a1r = 0.f, a1i = 0.f, a2r = 0.f, a2i = 0.f;
    const ST* xrow = &xs[r * 264];
    const float2* c0 = &ct[(n0 + 0) * 258];
    const float2* c1 = &ct[(n0 + 1) * 258];
    const float2* c2 = &ct[(n0 + 2) * 258];
#pragma unroll 8
    for (int wc = 0; wc < 256; wc += 4) {
        float x0, x1, x2, x3;
        if constexpr (BF) {
            ushort4 u = *reinterpret_cast<const ushort4*>(xrow + wc);
            x0 = bf2f(u.x); x1 = bf2f(u.y); x2 = bf2f(u.z); x3 = bf2f(u.w);
        } else {
            float4 f = *reinterpret_cast<const float4*>(xrow + wc);
            x0 = f.x; x1 = f.y; x2 = f.z; x3 = f.w;
        }
        float4 pa, pb;
        pa = *reinterpret_cast<const float4*>(c0 + wc);
        pb = *reinterpret_cast<const float4*>(c0 + wc + 2);
        a0r = fmaf(x0, pa.x, a0r); a0i = fmaf(x0, pa.y, a0i);
        a0r = fmaf(x1, pa.z, a0r); a0i = fmaf(x1, pa.w, a0i);
        a0r = fmaf(x2, pb.x, a0r); a0i = fmaf(x2, pb.y, a0i);
        a0r = fmaf(x3, pb.z, a0r); a0i = fmaf(x3, pb.w, a0i);
        pa = *reinterpret_cast<const float4*>(c1 + wc);
        pb = *reinterpret_cast<const float4*>(c1 + wc + 2);
        a1r = fmaf(x0, pa.x, a1r); a1i = fmaf(x0, pa.y, a1i);
        a1r = fmaf(x1, pa.z, a1r); a1i = fmaf(x1, pa.w, a1i);
        a1r = fmaf(x2, pb.x, a1r); a1i = fmaf(x2, pb.y, a1i);
        a1r = fmaf(x3, pb.z, a1r); a1i = fmaf(x3, pb.w, a1i);
        pa = *reinterpret_cast<const float4*>(c2 + wc);
        pb = *reinterpret_cast<const float4*>(c2 + wc + 2);
        a2r = fmaf(x0, pa.x, a2r); a2i = fmaf(x0, pa.y, a2i);
        a2r = fmaf(x1, pa.z, a2r); a2i = fmaf(x1, pa.w, a2i);
        a2r = fmaf(x2, pb.x, a2r); a2i = fmaf(x2, pb.y, a2i);
        a2r = fmaf(x3, pb.z, a2r); a2i = fmaf(x3, pb.w, a2i);
    }
    size_t bc = row0 >> 8;
    int hrow = (int)(row0 & 255) + r;
    float2* dst = Xw + (bc * 12) * 256 + hrow;
    dst[(size_t)(n0 + 0) * 256] = make_float2(a0r, a0i);
    dst[(size_t)(n0 + 1) * 256] = make_float2(a1r, a1i);
    dst[(size_t)(n0 + 2) * 256] = make_float2(a2r, a2i);
}

__global__ void k_rowdft(const float2* __restrict__ Xw, float2* __restrict__ F) {
    __shared__ float2 sm[12 * 257];
    int bc = blockIdx.x;
    const float2* src = Xw + (size_t)bc * 3072;
    for (int idx = threadIdx.x; idx < 3072; idx += 256) {
        int n = idx >> 8, hh = idx & 255;
        sm[n * 257 + hh] = src[idx];
    }
    __syncthreads();
    for (int j = threadIdx.x; j < 288; j += 256) {
        int n = j % 12, mm = j / 12;
        int meff = (mm < 12) ? mm : mm - 24;
        float s, c;
        __sincosf(-PI2 * (float)meff * (1.0f / 256.0f), &s, &c);
        float br = c, bi = s;
        float tr = 1.f, ti = 0.f, Fr = 0.f, Fi = 0.f;
        for (int hh = 0; hh < 256; hh++) {
            float2 xv = sm[n * 257 + hh];
            Fr = fmaf(xv.x, tr, Fr); Fr = fmaf(-xv.y, ti, Fr);
            Fi = fmaf(xv.x, ti, Fi); Fi = fmaf(xv.y, tr, Fi);
            float nr = tr * br - ti * bi;
            ti = tr * bi + ti * br;
            tr = nr;
        }
        F[(size_t)bc * 288 + j] = make_float2(Fr, Fi);
    }
}

__global__ void k_specmul(const float2* __restrict__ F,
                          const float* __restrict__ s1r, const float* __restrict__ s1i,
                          const float* __restrict__ s2r, const float* __restrict__ s2i,
                          float2* __restrict__ Y, int l) {
    __shared__ float2 wsh[4096];
    int mm = blockIdx.x / 12, n = blockIdx.x % 12;
    const float* wr; const float* wi; int m;
    if (mm < 12) { wr = s1r; wi = s1i; m = mm; }
    else         { wr = s2r; wi = s2i; m = mm - 12; }
    size_t base = (size_t)l * 589824 + (size_t)m * 12 + n;
    for (int idx = threadIdx.x; idx < 4096; idx += 256) {
        size_t a = base + (size_t)idx * 144;
        wsh[idx] = make_float2(wr[a], wi[a]);
    }
    __syncthreads();
    int o = threadIdx.x & 63, bq = threadIdx.x >> 6;
    for (int it = 0; it < 4; it++) {
        int b = bq * 4 + it;
        float Yr = 0.f, Yi = 0.f;
        const float2* Fb = F + (size_t)b * 64 * 288 + mm * 12 + n;
        for (int c = 0; c < 64; c++) {
            float2 fc = Fb[(size_t)c * 288];
            float2 wv = wsh[c * 64 + o];
            Yr = fmaf(fc.x, wv.x, Yr); Yr = fmaf(-fc.y, wv.y, Yr);
            Yi = fmaf(fc.x, wv.y, Yi); Yi = fmaf(fc.y, wv.x, Yi);
        }
        Y[((size_t)b * 64 + o) * 288 + mm * 12 + n] = make_float2(Yr, Yi);
    }
}

__global__ void k_expand(const float2* __restrict__ Y, float2* __restrict__ G) {
    int t = blockIdx.x * 256 + threadIdx.x;
    int hh = t & 255;
    int rem = t >> 8;
    int n = rem % 12, bo = rem / 12;
    const float2* Yb = Y + (size_t)bo * 288 + n;
    float s, c;
    __sincosf(PI2 * (float)hh * (1.0f / 256.0f), &s, &c);
    float br = c, bi = s;
    float tr = 1.f, ti = 0.f, Gr = 0.f, Gi = 0.f;
#pragma unroll
    for (int mm = 0; mm < 12; mm++) {
        float2 yv = Yb[mm * 12];
        Gr = fmaf(yv.x, tr, Gr); Gr = fmaf(-yv.y, ti, Gr);
        Gi = fmaf(yv.x, ti, Gi); Gi = fmaf(yv.y, tr, Gi);
        float nr = tr * br - ti * bi;
        ti = tr * bi + ti * br;
        tr = nr;
    }
    ti = -ti;
#pragma unroll
    for (int mm = 12; mm < 24; mm++) {
        float2 yv = Yb[mm * 12];
        Gr = fmaf(yv.x, tr, Gr); Gr = fmaf(-yv.y, ti, Gr);
        Gi = fmaf(yv.x, ti, Gi); Gi = fmaf(yv.y, tr, Gi);
        float nr = tr * br - ti * bi;
        ti = tr * bi + ti * br;
        tr = nr;
    }
    float sc = (n == 0 ? 1.0f : 2.0f) * (1.0f / 65536.0f);
    G[t] = make_float2(Gr * sc, Gi * sc);
}

template<bool BF>
__global__ __launch_bounds__(256) void k_update(
        typename HS<BF>::ST* __restrict__ h, const float2* __restrict__ G,
        const float* __restrict__ skw, const float* __restrict__ skb, int l) {
    __shared__ float hin[64 * 64];
    __shared__ float swT[64 * 68];
    __shared__ float2 Gs[64 * 12];
    __shared__ float2 ctab[12 * 64];
    int bx = blockIdx.x;
    int wt = bx & 3, hrow = (bx >> 2) & 255, b = bx >> 10;
    int w0 = wt * 64;
    int tid = threadIdx.x;
    size_t base4 = (size_t)b * 1048576 + (size_t)hrow * 64 + (w0 >> 2);
#pragma unroll
    for (int k = 0; k < 4; k++) {
        int idx = tid + k * 256;
        int c = idx >> 4, q = idx & 15;
        reinterpret_cast<float4*>(hin)[c * 16 + q] =
            HS<BF>::ld4(h, base4 + (size_t)c * 16384 + q);
    }
#pragma unroll
    for (int k = 0; k < 16; k++) {
        int idx = tid + k * 256;
        swT[(idx & 63) * 68 + (idx >> 6)] = skw[l * 4096 + idx];
    }
#pragma unroll
    for (int k = 0; k < 3; k++) {
        int idx = tid + k * 256;
        int o = idx / 12, n = idx % 12;
        Gs[idx] = G[(((size_t)b * 64 + o) * 12 + n) * 256 + hrow];
    }
#pragma unroll
    for (int k = 0; k < 3; k++) {
        int idx = tid + k * 256;
        int n = idx >> 6, wl = idx & 63;
        int r = (n * (w0 + wl)) & 255;
        float s, c;
        __sincosf(PI2 * (float)r * (1.0f / 256.0f), &s, &c);
        ctab[idx] = make_float2(c, s);
    }
    __syncthreads();
    int wq = tid & 15, oq = tid >> 4;
    float acc[4][4];
#pragma unroll
    for (int jo = 0; jo < 4; jo++) {
        float bias = skb[l * 64 + oq * 4 + jo];
#pragma unroll
        for (int jw = 0; jw < 4; jw++) acc[jo][jw] = bias;
    }
#pragma unroll
    for (int n = 0; n < 12; n++) {
        float2 g0 = Gs[(oq * 4 + 0) * 12 + n];
        float2 g1 = Gs[(oq * 4 + 1) * 12 + n];
        float2 g2 = Gs[(oq * 4 + 2) * 12 + n];
        float2 g3 = Gs[(oq * 4 + 3) * 12 + n];
#pragma unroll
        for (int jw = 0; jw < 4; jw++) {
            float2 cs = ctab[n * 64 + wq * 4 + jw];
            acc[0][jw] = fmaf(g0.x, cs.x, acc[0][jw]); acc[0][jw] = fmaf(-g0.y, cs.y, acc[0][jw]);
            acc[1][jw] = fmaf(g1.x, cs.x, acc[1][jw]); acc[1][jw] = fmaf(-g1.y, cs.y, acc[1][jw]);
            acc[2][jw] = fmaf(g2.x, cs.x, acc[2][jw]); acc[2][jw] = fmaf(-g2.y, cs.y, acc[2][jw]);
            acc[3][jw] = fmaf(g3.x, cs.x, acc[3][jw]); acc[3][jw] = fmaf(-g3.y, cs.y, acc[3][jw]);
        }
    }
    const float4* hin4 = reinterpret_cast<const float4*>(hin);
    const float4* swT4 = reinterpret_cast<const float4*>(swT);
#pragma unroll 4
    for (int c = 0; c < 64; c++) {
        float4 hv = hin4[c * 16 + wq];
        float4 wv = swT4[c * 17 + oq];
        acc[0][0] = fmaf(wv.x, hv.x, acc[0][0]); acc[0][1] = fmaf(wv.x, hv.y, acc[0][1]);
        acc[0][2] = fmaf(wv.x, hv.z, acc[0][2]); acc[0][3] = fmaf(wv.x, hv.w, acc[0][3]);
        acc[1][0] = fmaf(wv.y, hv.x, acc[1][0]); acc[1][1] = fmaf(wv.y, hv.y, acc[1][1]);
        acc[1][2] = fmaf(wv.y, hv.z, acc[1][2]); acc[1][3] = fmaf(wv.y, hv.w, acc[1][3]);
        acc[2][0] = fmaf(wv.z, hv.x, acc[2][0]); acc[2][1] = fmaf(wv.z, hv.y, acc[2][1]);
        acc[2][2] = fmaf(wv.z, hv.z, acc[2][2]); acc[2][3] = fmaf(wv.z, hv.w, acc[2][3]);
        acc[3][0] = fmaf(wv.w, hv.x, acc[3][0]); acc[3][1] = fmaf(wv.w, hv.y, acc[3][1]);
        acc[3][2] = fmaf(wv.w, hv.z, acc[3][2]); acc[3][3] = fmaf(wv.w, hv.w, acc[3][3]);
    }
#pragma unroll
    for (int jo = 0; jo < 4; jo++) {
        int o = oq * 4 + jo;
        float4 r;
        r.x = gelu_exact(acc[jo][0]); r.y = gelu_exact(acc[jo][1]);
        r.z = gelu_exact(acc[jo][2]); r.w = gelu_exact(acc[jo][3]);
        HS<BF>::st4(h, base4 + (size_t)o * 16384 + wq, r);
    }
}

template<bool BF>
__global__ void k_proj(const typename HS<BF>::ST* __restrict__ h, const float* __restrict__ pw,
                       const float* __restrict__ pb, float* __restrict__ out) {
    int i = blockIdx.x * 256 + threadIdx.x;
    int b = i >> 14, p4 = i & 16383;
    size_t hb = (size_t)b * 1048576 + p4;
    float4 acc = make_float4(0.f, 0.f, 0.f, 0.f);
#pragma unroll 8
    for (int c = 0; c < 64; c++) {
        float4 hv = HS<BF>::ld4(h, hb + (size_t)c * 16384);
        float wv = pw[c];
        acc.x = fmaf(hv.x, wv, acc.x); acc.y = fmaf(hv.y, wv, acc.y);
        acc.z = fmaf(hv.z, wv, acc.z); acc.w = fmaf(hv.w, wv, acc.w);
    }
    float bias = pb[0];
    acc.x += bias; acc.y += bias; acc.z += bias; acc.w += bias;
    reinterpret_cast<float4*>(out)[i] = acc;
}

// ============================ fused MFMA path (tier B) ======================
// G / Xw packed chunks (aliased buffer GXw, ushort): per (b,hrow) 3072 ushort:
//   [hi: 64 o x 24 k2][lo: 64 o x 24 k2], element (o, k2=2n+comp): o*24+n*2+comp
// Tg table (global ushort, 159,744 B): see R6 comment.
#define SKWHI 22528
#define SKWLO 38912
#define TW2US 55296
__global__ __launch_bounds__(256) void k_ttab(unsigned short* __restrict__ Tg,
                                              const float* __restrict__ skw) {
    int idx = blockIdx.x * 256 + threadIdx.x;     // 312*256 = 79872
    if (idx >= 79872) return;
    if (idx < 16384) {
        int q = idx & 8191;
        int w = q >> 5, b3 = (q >> 3) & 3;
        int k2 = ((b3 ^ (w & 3)) << 3) | (q & 7);
        float v = 0.f;
        if (k2 < 24) {
            int n = k2 >> 1, r = (n * w) & 255;
            float s, c;
            __sincosf(PI2 * (float)r * (1.0f / 256.0f), &s, &c);
            v = (k2 & 1) ? s : c;
        }
        if (idx < 8192) Tg[idx] = f2bf(v);
        else { unsigned short hi = f2bf(v); Tg[idx] = f2bf(v - bf2f(hi)); }
    } else if (idx < 22528) {
        int q = idx - 16384;
        int n2 = q >> 8, t = q & 255;
        int w = (((t >> 3) ^ (n2 & 7)) << 3) | (t & 7);
        int n = n2 >> 1, r = (n * w) & 255;
        float s, c;
        __sincosf(PI2 * (float)r * (1.0f / 256.0f), &s, &c);
        Tg[idx] = f2bf((n2 & 1) ? s : c);
    } else if (idx < 55296) {
        int q = idx - SKWHI;
        int lo = (q >= 16384);
        q &= 16383;
        float w = skw[q];
        unsigned short hi = f2bf(w);
        Tg[idx] = lo ? f2bf(w - bf2f(hi)) : hi;
    } else {
        int j = idx - TW2US;                      // 0..24575, one float each
        int pair = j >> 1, comp = j & 1;
        int mm = pair >> 8, hh = pair & 255;
        int meff = (mm < 12) ? mm : mm - 24;
        int r = (((-(meff * hh)) % 256) + 256) & 255;
        float s, c;
        __sincosf(PI2 * (float)r * (1.0f / 256.0f), &s, &c);
        reinterpret_cast<float*>(Tg + TW2US)[j] = comp ? s : c;
    }
}

// layer-0 Xw chunks via the rank-1 lift identity
__global__ __launch_bounds__(256) void k_xw0(const float* __restrict__ xg,
                                             const float* __restrict__ lw,
                                             const float* __restrict__ lb,
                                             unsigned short* __restrict__ Xwp) {
    __shared__ float xr[256];
    __shared__ float part[24][9];
    __shared__ float xh[24];
    int blk = blockIdx.x;                         // b*256 + hrow
    int tid = threadIdx.x;
    if (tid < 64)
        reinterpret_cast<float4*>(xr)[tid] =
            reinterpret_cast<const float4*>(xg + (size_t)blk * 256)[tid];
    __syncthreads();
    if (tid < 192) {
        int n2 = tid % 24, seg = tid / 24;
        int n = n2 >> 1, comp = n2 & 1;
        float acc = 0.f;
#pragma unroll 8
        for (int j = 0; j < 32; j++) {
            int w = seg * 32 + j;
            int r = (n * w) & 255;
            float s, c;
            __sincosf(PI2 * (float)r * (1.0f / 256.0f), &s, &c);
            acc = fmaf(xr[w], comp ? -s : c, acc);
        }
        part[n2][seg] = acc;
    }
    __syncthreads();
    if (tid < 24) {
        float a = 0.f;
#pragma unroll
        for (int s = 0; s < 8; s++) a += part[tid][s];
        xh[tid] = a;
    }
    __syncthreads();
    unsigned* dstw = reinterpret_cast<unsigned*>(Xwp + (size_t)blk * 3072);
#pragma unroll
    for (int q = 0; q < 3; q++) {
        int i = tid + q * 256;
        int c = i / 12, n = i % 12;
        float wr = lw[c];
        float re = fmaf(wr, xh[2 * n], (n == 0) ? lb[c] * 256.0f : 0.0f);
        float im = wr * xh[2 * n + 1];
        unsigned short hre = f2bf(re), him = f2bf(im);
        unsigned short lre = f2bf(re - bf2f(hre)), lim = f2bf(im - bf2f(him));
        dstw[i] = (unsigned)hre | ((unsigned)him << 16);
        dstw[768 + i] = (unsigned)lre | ((unsigned)lim << 16);
    }
}

// row DFT reading packed Xw chunks — b128 vectorized, 2 accumulator pairs
__global__ __launch_bounds__(256) void k_rowdft2t(const unsigned short* __restrict__ Xwp,
                                                  float2* __restrict__ F,
                                                  const float2* __restrict__ tw2) {
    __shared__ __align__(16) float2 sm[12 * 258];
    int bc = blockIdx.x;
    int b = bc >> 6, c = bc & 63;
    for (int idx = threadIdx.x; idx < 3072; idx += 256) {
        int hh = idx / 12, n = idx % 12;
        size_t base = ((size_t)(b * 256 + hh)) * 3072 + c * 24 + n * 2;
        unsigned hi = *reinterpret_cast<const unsigned*>(Xwp + base);
        unsigned lo = *reinterpret_cast<const unsigned*>(Xwp + base + 1536);
        float re = bf2f((unsigned short)(hi & 0xffff)) + bf2f((unsigned short)(lo & 0xffff));
        float im = bf2f((unsigned short)(hi >> 16)) + bf2f((unsigned short)(lo >> 16));
        sm[n * 258 + hh] = make_float2(re, im);
    }
    __syncthreads();
    for (int j = threadIdx.x; j < 288; j += 256) {
        int n = j % 12, mm = j / 12;
        const float4* twp = reinterpret_cast<const float4*>(tw2 + mm * 256);
        const float4* smp = reinterpret_cast<const float4*>(&sm[n * 258]);
        float Fr0 = 0.f, Fi0 = 0.f, Fr1 = 0.f, Fi1 = 0.f;
#pragma unroll 8
        for (int p = 0; p < 128; p++) {
            float4 xv = smp[p];                   // 2 complex samples
            float4 wv = twp[p];
            Fr0 = fmaf(xv.x, wv.x, Fr0); Fr0 = fmaf(-xv.y, wv.y, Fr0);
            Fi0 = fmaf(xv.x, wv.y, Fi0); Fi0 = fmaf(xv.y, wv.x, Fi0);
            Fr1 = fmaf(xv.z, wv.z, Fr1); Fr1 = fmaf(-xv.w, wv.w, Fr1);
            Fi1 = fmaf(xv.z, wv.w, Fi1); Fi1 = fmaf(xv.w, wv.z, Fi1);
        }
        F[(size_t)bc * 288 + j] = make_float2(Fr0 + Fr1, Fi0 + Fi1);
    }
}

// specmul, high-MLP version: 1024 threads, b folded into the thread grid
__global__ __launch_bounds__(1024) void k_specmul2(const float2* __restrict__ F,
                          const float* __restrict__ s1r, const float* __restrict__ s1i,
                          const float* __restrict__ s2r, const float* __restrict__ s2i,
                          float2* __restrict__ Y, int l) {
    __shared__ float2 wsh[4096];
    __shared__ float2 fsh[1024];
    int mm = blockIdx.x / 12, n = blockIdx.x % 12;
    const float* wr; const float* wi; int m;
    if (mm < 12) { wr = s1r; wi = s1i; m = mm; }
    else         { wr = s2r; wi = s2i; m = mm - 12; }
    size_t base = (size_t)l * 589824 + (size_t)m * 12 + n;
    int tid = threadIdx.x;
#pragma unroll
    for (int k = 0; k < 4; k++) {
        int idx = tid + k * 1024;                 // idx = c*64+o
        size_t a = base + (size_t)idx * 144;
        wsh[idx] = make_float2(wr[a], wi[a]);
    }
    fsh[tid] = F[(size_t)tid * 288 + mm * 12 + n];  // tid = b*64+c
    __syncthreads();
    int o = tid & 63, b = tid >> 6;
    const float2* fb = &fsh[b * 64];
    float Yr = 0.f, Yi = 0.f;
#pragma unroll 8
    for (int c = 0; c < 64; c++) {
        float2 fc = fb[c];
        float2 wv = wsh[c * 64 + o];
        Yr = fmaf(fc.x, wv.x, Yr); Yr = fmaf(-fc.y, wv.y, Yr);
        Yi = fmaf(fc.x, wv.y, Yi); Yi = fmaf(fc.y, wv.x, Yi);
    }
    Y[((size_t)(b * 64 + o)) * 288 + mm * 12 + n] = make_float2(Yr, Yi);
}

// expand writing packed G chunks (re, -im) hi/lo, block = (b, hh)
__global__ __launch_bounds__(256) void k_expand2(const float2* __restrict__ Y,
                                                 unsigned short* __restrict__ Gpk) {
    __shared__ float2 tw[24];
    int blk = blockIdx.x;
    int hh = blk & 255, b = blk >> 8;
    int t = threadIdx.x;
    if (t < 24) {
        int meff = (t < 12) ? t : t - 24;
        int r = (meff * hh) & 255;
        float s, c;
        __sincosf(PI2 * (float)r * (1.0f / 256.0f), &s, &c);
        tw[t] = make_float2(c, s);
    }
    __syncthreads();
    const float2* Yb = Y + (size_t)b * 64 * 288;
    unsigned short* Gb = Gpk + ((size_t)(b * 256 + hh)) * 3072;
#pragma unroll
    for (int q = 0; q < 3; q++) {
        int i = t * 3 + q;
        int o = i / 12, n = i % 12;
        const float2* Yp = Yb + o * 288 + n;
        float Gr = 0.f, Gi = 0.f;
#pragma unroll
        for (int mm = 0; mm < 24; mm++) {
            float2 yv = Yp[mm * 12];
            float2 w = tw[mm];
            Gr = fmaf(yv.x, w.x, Gr); Gr = fmaf(-yv.y, w.y, Gr);
            Gi = fmaf(yv.x, w.y, Gi); Gi = fmaf(yv.y, w.x, Gi);
        }
        float sc = (n == 0 ? 1.0f : 2.0f) * (1.0f / 65536.0f);
        float gr = Gr * sc, gi = -Gi * sc;
        unsigned short hre = f2bf(gr), him = f2bf(gi);
        unsigned short lre = f2bf(gr - bf2f(hre)), lim = f2bf(gi - bf2f(him));
        int off = o * 24 + n * 2;
        *reinterpret_cast<unsigned*>(Gb + off) = (unsigned)hre | ((unsigned)him << 16);
        *reinterpret_cast<unsigned*>(Gb + 1536 + off) = (unsigned)lre | ((unsigned)lim << 16);
    }
}

// fused: transposed GEMM (D=[w][o]) + gelu + {h write | proj} + {colDFT | -}.
// hnew lives IN the hT region as XOR-swizzled [64][256]:
//   elem (o,w) at o*256 + (w ^ ((o&7)<<3))   -> LDS = 32 KB, 5 blocks/CU.
// launch_bounds min-waves = 4 (NOT 5): R11 showed 5 strangles VGPR -> spill.
// Staging uses c-quad b64 writes: 16 banks/half-wave = 2-way (free) vs the
// old b32 c-pair scheme's 8 banks = 4-way.
template<bool FIRST, bool LAST>
__global__ __launch_bounds__(256, 4) void k_fused3(
        unsigned short* hg, const float* __restrict__ xg,
        const float* __restrict__ lw, const float* __restrict__ lb,
        unsigned short* GXw, const float* __restrict__ skb,
        const float* __restrict__ pw, const float* __restrict__ pb,
        float* __restrict__ outg, const unsigned short* __restrict__ Tg, int l) {
    __shared__ __align__(16) unsigned short lds[16384];   // hT | hnew (swizzled)
    int tid = threadIdx.x, lane = tid & 63, wid = tid >> 6;
    int lr = lane & 15, lg = lane >> 4;
    int bx = blockIdx.x;
    int hrow = bx & 255, b = bx >> 8;

    // ---- stage hT[w][c] (swizzled) ----
    if constexpr (FIRST) {
#pragma unroll
        for (int k = 0; k < 4; k++) {
            int pidx = tid + k * 256;
            int cp = pidx >> 5, w0 = (pidx & 31) * 8;
            int c0 = cp * 2;
            float wa = lw[c0], ba = lb[c0];
            float wb = lw[c0 + 1], bb = lb[c0 + 1];
            float4 xv0 = *reinterpret_cast<const float4*>(xg + (size_t)bx * 256 + w0);
            float4 xv1 = *reinterpret_cast<const float4*>(xg + (size_t)bx * 256 + w0 + 4);
            float xv[8] = {xv0.x, xv0.y, xv0.z, xv0.w, xv1.x, xv1.y, xv1.z, xv1.w};
            int sl = (c0 >> 3) & 7, cl = c0 & 7;
#pragma unroll
            for (int j = 0; j < 8; j++) {
                int w = w0 + j;
                float h0 = fmaf(xv[j], wa, ba);
                float h1 = fmaf(xv[j], wb, bb);
                int Xws = (w & 7) ^ ((w >> 3) & 7);
                *reinterpret_cast<unsigned*>(&lds[w * 64 + (((sl ^ Xws) & 7) << 3) + cl]) =
                    cvtpk_bf16(h0, h1);
            }
        }
    } else {
        // c-quad staging: 512 items = 16 quads x 32 w-chunks; b64 LDS writes
#pragma unroll
        for (int k = 0; k < 2; k++) {
            int item = tid + k * 256;
            int q = item >> 5, w0 = (item & 31) * 8;
            int c0 = q * 4;
            const unsigned short* s0 = hg + ((size_t)(b * 64 + c0) * 256 + hrow) * 256 + w0;
            uint4 v0 = *reinterpret_cast<const uint4*>(s0);
            uint4 v1 = *reinterpret_cast<const uint4*>(s0 + 65536);
            uint4 v2 = *reinterpret_cast<const uint4*>(s0 + 131072);
            uint4 v3 = *reinterpret_cast<const uint4*>(s0 + 196608);
            unsigned a01[8], a23[8];
            a01[0] = perm_lo(v0.x, v1.x); a01[1] = perm_hi(v0.x, v1.x);
            a01[2] = perm_lo(v0.y, v1.y); a01[3] = perm_hi(v0.y, v1.y);
            a01[4] = perm_lo(v0.z, v1.z); a01[5] = perm_hi(v0.z, v1.z);
            a01[6] = perm_lo(v0.w, v1.w); a01[7] = perm_hi(v0.w, v1.w);
            a23[0] = perm_lo(v2.x, v3.x); a23[1] = perm_hi(v2.x, v3.x);
            a23[2] = perm_lo(v2.y, v3.y); a23[3] = perm_hi(v2.y, v3.y);
            a23[4] = perm_lo(v2.z, v3.z); a23[5] = perm_hi(v2.z, v3.z);
            a23[6] = perm_lo(v2.w, v3.w); a23[7] = perm_hi(v2.w, v3.w);
            int sl = (c0 >> 3) & 7, cl = c0 & 7;   // cl in {0,4}
#pragma unroll
            for (int j = 0; j < 8; j++) {
                int w = w0 + j;
                int Xws = (w & 7) ^ ((w >> 3) & 7);
                u32x2 pk;
                pk[0] = a01[j]; pk[1] = a23[j];
                *reinterpret_cast<u32x2*>(&lds[w * 64 + (((sl ^ Xws) & 7) << 3) + cl]) = pk;
            }
        }
    }
    // ---- B fragments: skw hi/lo + G hi/lo, col o = wid*16+lr ----
    int oA = wid * 16 + lr;
    bf16x8 bs_h[2], bs_l[2];
#pragma unroll
    for (int ks = 0; ks < 2; ks++) {
        int off = l * 4096 + oA * 64 + ks * 32 + lg * 8;
        bs_h[ks] = __builtin_bit_cast(bf16x8,
            *reinterpret_cast<const u32x4*>(Tg + SKWHI + off));
        bs_l[ks] = __builtin_bit_cast(bf16x8,
            *reinterpret_cast<const u32x4*>(Tg + SKWLO + off));
    }
    int lgc = (lg < 3) ? lg : 2;
    size_t gbase = ((size_t)(b * 256 + hrow)) * 3072 + (size_t)oA * 24 + lgc * 8;
    u32x4 ghv = *reinterpret_cast<const u32x4*>(GXw + gbase);
    u32x4 glv = *reinterpret_cast<const u32x4*>(GXw + gbase + 1536);
    if (lg == 3) { ghv = (u32x4){0, 0, 0, 0}; glv = (u32x4){0, 0, 0, 0}; }
    bf16x8 bg_h = __builtin_bit_cast(bf16x8, ghv);
    bf16x8 bg_l = __builtin_bit_cast(bf16x8, glv);
    float bias_o = skb[l * 64 + oA];
    f32x4 binit = {bias_o, bias_o, bias_o, bias_o};

    __syncthreads();

    // ---- main GEMM (operand-swapped): acc[wt] = D'[w][o] tile ----
    f32x4 acc[16];
#pragma unroll
    for (int wt = 0; wt < 16; wt++) acc[wt] = binit;
    __builtin_amdgcn_s_setprio(1);
#pragma unroll
    for (int wt = 0; wt < 16; wt++) {
        int w = wt * 16 + lr;
        int Xws = (w & 7) ^ ((w >> 3) & 7);
        int i0 = w * 64 + (((lg ^ Xws) & 7) << 3);
        int i1 = w * 64 + ((((4 + lg) ^ Xws) & 7) << 3);
        int it = w * 32 + (((lg ^ (w & 3)) & 3) << 3);
        bf16x8 A0 = __builtin_bit_cast(bf16x8, *reinterpret_cast<const u32x4*>(&lds[i0]));
        bf16x8 A1 = __builtin_bit_cast(bf16x8, *reinterpret_cast<const u32x4*>(&lds[i1]));
        bf16x8 Th = __builtin_bit_cast(bf16x8, *reinterpret_cast<const u32x4*>(Tg + it));
        bf16x8 Tl = __builtin_bit_cast(bf16x8, *reinterpret_cast<const u32x4*>(Tg + 8192 + it));
        acc[wt] = __builtin_amdgcn_mfma_f32_16x16x32_bf16(A0, bs_h[0], acc[wt], 0, 0, 0);
        acc[wt] = __builtin_amdgcn_mfma_f32_16x16x32_bf16(A0, bs_l[0], acc[wt], 0, 0, 0);
        acc[wt] = __builtin_amdgcn_mfma_f32_16x16x32_bf16(A1, bs_h[1], acc[wt], 0, 0, 0);
        acc[wt] = __builtin_amdgcn_mfma_f32_16x16x32_bf16(A1, bs_l[1], acc[wt], 0, 0, 0);
        acc[wt] = __builtin_amdgcn_mfma_f32_16x16x32_bf16(Th, bg_h, acc[wt], 0, 0, 0);
        acc[wt] = __builtin_amdgcn_mfma_f32_16x16x32_bf16(Tl, bg_h, acc[wt], 0, 0, 0);
        acc[wt] = __builtin_amdgcn_mfma_f32_16x16x32_bf16(Th, bg_l, acc[wt], 0, 0, 0);
    }
    __builtin_amdgcn_s_setprio(0);
    __syncthreads();                              // hT dead

    // ---- epilogue: gelu + cvt_pk -> swizzled hnew (b64 writes) ----
    int wD = lg * 4;
    int osw = (oA & 7) << 3;
#pragma unroll
    for (int wt = 0; wt < 16; wt++) {
        float v0 = gelu_fast(acc[wt][0]);
        float v1 = gelu_fast(acc[wt][1]);
        float v2 = gelu_fast(acc[wt][2]);
        float v3 = gelu_fast(acc[wt][3]);
        u32x2 pk;
        pk[0] = cvtpk_bf16(v0, v1);
        pk[1] = cvtpk_bf16(v2, v3);
        *reinterpret_cast<u32x2*>(&lds[oA * 256 + ((wt * 16 + wD) ^ osw)]) = pk;
    }
    __syncthreads();

    if constexpr (LAST) {
        // ---- proj-reduce: out[b,hrow,w] = pb + sum_o pw[o]*hnew[o][w] ----
        float accp = pb[0];
#pragma unroll 8
        for (int o = 0; o < 64; o++)
            accp = fmaf(pw[o], bf2f(lds[o * 256 + (tid ^ ((o & 7) << 3))]), accp);
        outg[(size_t)bx * 256 + tid] = accp;
        return;
    }

    // ---- copy hnew -> global (coalesced; swizzled b128 LDS reads) ----
#pragma unroll
    for (int k = 0; k < 8; k++) {
        int chi = k * 256 + tid;
        int o = chi >> 5, wq = (chi & 31) * 8;
        u32x4 v = *reinterpret_cast<const u32x4*>(&lds[o * 256 + (wq ^ ((o & 7) << 3))]);
        *reinterpret_cast<u32x4*>(hg + ((size_t)(b * 64 + o) * 256 + hrow) * 256 + wq) = v;
    }
    // ---- fused column-DFT for next layer ----
    f32x4 acc2[2];
    acc2[0] = (f32x4){0.f, 0.f, 0.f, 0.f};
    acc2[1] = (f32x4){0.f, 0.f, 0.f, 0.f};
    int oa = wid * 16 + lr;
    int oasw = (oa & 7) << 3;
#pragma unroll
    for (int sg = 0; sg < 8; sg++) {
        int wb = 4 * sg + lg;
        bf16x8 Af = __builtin_bit_cast(bf16x8,
            *reinterpret_cast<const u32x4*>(&lds[oa * 256 + ((wb * 8) ^ oasw)]));
#pragma unroll
        for (int nt = 0; nt < 2; nt++) {
            int n2 = nt * 16 + lr;
            int n2r = (n2 < 24) ? n2 : 23;        // cols >=24 discarded
            bf16x8 Bf = __builtin_bit_cast(bf16x8, *reinterpret_cast<const u32x4*>(
                Tg + 16384 + n2r * 256 + ((wb ^ (n2r & 7)) << 3)));
            acc2[nt] = __builtin_amdgcn_mfma_f32_16x16x32_bf16(Af, Bf, acc2[nt], 0, 0, 0);
        }
    }
    __syncthreads();                              // hnew LDS dead
    // ---- pack Xw (bf16 hi/lo) into LDS chunk, then coalesced copy out ----
    int oD = wid * 16 + lg * 4;
#pragma unroll
    for (int nt = 0; nt < 2; nt++) {
        int n2 = nt * 16 + lr;
        if (n2 < 24) {
            float sgn = (n2 & 1) ? -1.f : 1.f;
#pragma unroll
            for (int r = 0; r < 4; r++) {
                float v = sgn * acc2[nt][r];
                unsigned short hv = f2bf(v);
                unsigned short lv = f2bf(v - bf2f(hv));
                int o = oD + r;
                lds[o * 24 + n2] = hv;
                lds[1536 + o * 24 + n2] = lv;
            }
        }
    }
    __syncthreads();
    unsigned* dstw = reinterpret_cast<unsigned*>(GXw + ((size_t)(b * 256 + hrow)) * 3072);
    const unsigned* srcw = reinterpret_cast<const unsigned*>(lds);
#pragma unroll
    for (int q = 0; q < 3; q++) {
        int i = tid + q * 256;                    // 768 u32
        dstw[i] = srcw[i];
    }
}

// ============================ dispatch ======================================

template<bool BF>
static void run_pipeline_old(void* const* d_in, void* d_out, void* d_ws, hipStream_t stream) {
    const float* x   = (const float*)d_in[0];
    const float* lw  = (const float*)d_in[1];
    const float* lb  = (const float*)d_in[2];
    const float* s1r = (const float*)d_in[3];
    const float* s1i = (const float*)d_in[4];
    const float* s2r = (const float*)d_in[5];
    const float* s2i = (const float*)d_in[6];
    const float* skw = (const float*)d_in[7];
    const float* skb = (const float*)d_in[8];
    const float* pw  = (const float*)d_in[9];
    const float* pb  = (const float*)d_in[10];
    float* out = (float*)d_out;
    char* ws = (char*)d_ws;
    using ST = typename HS<BF>::ST;
    size_t hbytes = 67108864ull * sizeof(ST);
    ST*     hbuf = (ST*)ws;
    float2* XwG  = (float2*)(ws + hbytes);
    float2* F    = (float2*)(ws + hbytes + 25165824ull);
    float2* Y    = (float2*)(ws + hbytes + 25165824ull + 2359296ull);
    k_lift<BF><<<65536, 256, 0, stream>>>(x, lw, lb, hbuf);
    for (int l = 0; l < 4; l++) {
        k_coldft<BF><<<4096, 256, 0, stream>>>(hbuf, XwG);
        k_rowdft <<<1024,  256, 0, stream>>>(XwG, F);
        k_specmul<<<288,   256, 0, stream>>>(F, s1r, s1i, s2r, s2i, Y, l);
        k_expand <<<12288, 256, 0, stream>>>(Y, XwG);
        k_update<BF><<<16384, 256, 0, stream>>>(hbuf, XwG, skw, skb, l);
    }
    k_proj<BF><<<1024, 256, 0, stream>>>(hbuf, pw, pb, out);
}

static void run_pipeline_fused(void* const* d_in, void* d_out, void* d_ws, hipStream_t stream) {
    const float* x   = (const float*)d_in[0];
    const float* lw  = (const float*)d_in[1];
    const float* lb  = (const float*)d_in[2];
    const float* s1r = (const float*)d_in[3];
    const float* s1i = (const float*)d_in[4];
    const float* s2r = (const float*)d_in[5];
    const float* s2i = (const float*)d_in[6];
    const float* skw = (const float*)d_in[7];
    const float* skb = (const float*)d_in[8];
    const float* pw  = (const float*)d_in[9];
    const float* pb  = (const float*)d_in[10];
    float* out = (float*)d_out;
    char* ws = (char*)d_ws;
    unsigned short* hbuf = (unsigned short*)ws;
    unsigned short* XwG  = (unsigned short*)(ws + 134217728ull);
    float2* F   = (float2*)(ws + 134217728ull + 25165824ull);
    float2* Y   = (float2*)(ws + 134217728ull + 25165824ull + 2359296ull);
    unsigned short* Tg = (unsigned short*)(ws + 164102144ull);
    const float2* tw2 = (const float2*)((char*)Tg + 110592);

    k_ttab<<<312, 256, 0, stream>>>(Tg, skw);
    k_xw0<<<4096, 256, 0, stream>>>(x, lw, lb, XwG);
    for (int l = 0; l < 4; l++) {
        k_rowdft2t<<<1024, 256, 0, stream>>>(XwG, F, tw2);
        k_specmul2<<<288, 1024, 0, stream>>>(F, s1r, s1i, s2r, s2i, Y, l);
        k_expand2<<<4096, 256, 0, stream>>>(Y, XwG);
        if (l == 0)
            k_fused3<true, false><<<4096, 256, 0, stream>>>(hbuf, x, lw, lb, XwG, skb, pw, pb, out, Tg, l);
        else if (l == 3)
            k_fused3<false, true><<<4096, 256, 0, stream>>>(hbuf, x, lw, lb, XwG, skb, pw, pb, out, Tg, l);
        else
            k_fused3<false, false><<<4096, 256, 0, stream>>>(hbuf, x, lw, lb, XwG, skb, pw, pb, out, Tg, l);
    }
}

extern "C" void kernel_launch(void* const* d_in, const int* in_sizes, int n_in,
                              void* d_out, int out_size, void* d_ws, size_t ws_size,
                              hipStream_t stream) {
    // fused tier: 164,102,144 (bf16 h + XwG + F + Y) + 159,744 (Tg) = 164,261,888
    if (ws_size >= 164261888ull) {
        run_pipeline_fused(d_in, d_out, d_ws, stream);
    } else {
        run_pipeline_old<true>(d_in, d_out, d_ws, stream);
    }
}

// Round 18
// 739.617 us; speedup vs baseline: 1.1147x; 1.0499x over previous
//
#include <hip/hip_runtime.h>
#include <math.h>

#define PI2 6.283185307179586f

typedef short  bf16x8 __attribute__((ext_vector_type(8)));
typedef float  f32x4  __attribute__((ext_vector_type(4)));
typedef unsigned int u32x4 __attribute__((ext_vector_type(4)));
typedef unsigned int u32x2 __attribute__((ext_vector_type(2)));

__device__ __forceinline__ float gelu_exact(float x) {
    return 0.5f * x * (1.0f + erff(x * 0.70710678118654752f));
}
__device__ __forceinline__ float rcp_fast(float x) {
    float r;
    asm("v_rcp_f32 %0, %1" : "=v"(r) : "v"(x));
    return r;
}
// branch-free gelu: AS 7.1.26 erf (abs err 1.5e-7); raw v_rcp (arg>=1, ~1ulp)
__device__ __forceinline__ float gelu_fast(float x) {
    float ax = __builtin_fabsf(x);
    float s  = ax * 0.70710678118654752f;
    float t  = rcp_fast(fmaf(0.3275911f, s, 1.0f));
    float u  = fmaf(t, 1.061405429f, -1.453152027f);
    u = fmaf(t, u, 1.421413741f);
    u = fmaf(t, u, -0.284496736f);
    u = fmaf(t, u, 0.254829592f);
    float p  = t * u;
    float e  = __expf(-s * s);
    float q  = 0.5f * ax;
    return fmaf(-q * p, e, fmaf(0.5f, x, q));
}
__device__ __forceinline__ float bf2f(unsigned short u) {
    return __uint_as_float(((unsigned int)u) << 16);
}
__device__ __forceinline__ unsigned short f2bf(float f) {
    unsigned int b = __float_as_uint(f);
    unsigned int r = (b + 0x7FFFu + ((b >> 16) & 1u)) >> 16;   // RNE
    return (unsigned short)r;
}
__device__ __forceinline__ unsigned cvtpk_bf16(float lo, float hi) {
    unsigned r;
    asm("v_cvt_pk_bf16_f32 %0, %1, %2" : "=v"(r) : "v"(lo), "v"(hi));
    return r;
}
// result = lo16(a) | lo16(b)<<16  (1 inst)
__device__ __forceinline__ unsigned perm_lo(unsigned a, unsigned b) {
    unsigned r;
    asm("v_perm_b32 %0, %1, %2, %3" : "=v"(r) : "v"(b), "v"(a), "s"(0x05040100u));
    return r;
}
// result = hi16(a) | hi16(b)<<16  (1 inst)
__device__ __forceinline__ unsigned perm_hi(unsigned a, unsigned b) {
    unsigned r;
    asm("v_perm_b32 %0, %1, %2, %3" : "=v"(r) : "v"(b), "v"(a), "s"(0x07060302u));
    return r;
}

template<bool BF> struct HS;
template<> struct HS<false> {
    using ST = float;
    static __device__ __forceinline__ float4 ld4(const ST* p, size_t i4) {
        return reinterpret_cast<const float4*>(p)[i4];
    }
    static __device__ __forceinline__ void st4(ST* p, size_t i4, float4 v) {
        reinterpret_cast<float4*>(p)[i4] = v;
    }
};
template<> struct HS<true> {
    using ST = unsigned short;
    static __device__ __forceinline__ float4 ld4(const ST* p, size_t i4) {
        ushort4 u = reinterpret_cast<const ushort4*>(p)[i4];
        return make_float4(bf2f(u.x), bf2f(u.y), bf2f(u.z), bf2f(u.w));
    }
    static __device__ __forceinline__ void st4(ST* p, size_t i4, float4 v) {
        ushort4 u = make_ushort4(f2bf(v.x), f2bf(v.y), f2bf(v.z), f2bf(v.w));
        reinterpret_cast<ushort4*>(p)[i4] = u;
    }
};

// ============================ fallback-tier kernels =========================

template<bool BF>
__global__ void k_lift(const float* __restrict__ x, const float* __restrict__ lw,
                       const float* __restrict__ lb, typename HS<BF>::ST* __restrict__ h) {
    int i = blockIdx.x * 256 + threadIdx.x;
    int p4 = i & 16383;
    int bc = i >> 14;
    int c = bc & 63, b = bc >> 6;
    float4 xv = reinterpret_cast<const float4*>(x)[(size_t)b * 16384 + p4];
    float w = lw[c], bias = lb[c];
    float4 o;
    o.x = fmaf(xv.x, w, bias); o.y = fmaf(xv.y, w, bias);
    o.z = fmaf(xv.z, w, bias); o.w = fmaf(xv.w, w, bias);
    HS<BF>::st4(h, i, o);
}

template<bool BF>
__global__ __launch_bounds__(256) void k_coldft(const typename HS<BF>::ST* __restrict__ h,
                                                float2* __restrict__ Xw) {
    using ST = typename HS<BF>::ST;
    __shared__ __align__(16) ST xs[64 * 264];
    __shared__ __align__(16) float2 ct[12 * 258];
    int tid = threadIdx.x;
    size_t row0 = (size_t)blockIdx.x * 64;
#pragma unroll
    for (int k = 0; k < 12; k++) {
        int idx = tid + k * 256;
        int n = idx >> 8, w = idx & 255;
        int rr = (n * w) & 255;
        float s, c;
        __sincosf(PI2 * (float)rr * (1.0f / 256.0f), &s, &c);
        ct[n * 258 + w] = make_float2(c, -s);
    }
    const ST* src = h + row0 * 256;
    if constexpr (BF) {
#pragma unroll
        for (int k = 0; k < 8; k++) {
            int i = (tid + k * 256) * 8;
            int r = i >> 8, w = i & 255;
            uint4 v = *reinterpret_cast<const uint4*>(src + i);
            *reinterpret_cast<uint4*>(&xs[r * 264 + w]) = v;
        }
    } else {
#pragma unroll
        for (int k = 0; k < 16; k++) {
            int i = (tid + k * 256) * 4;
            int r = i >> 8, w = i & 255;
            float4 v = *reinterpret_cast<const float4*>(src + i);
            *reinterpret_cast<float4*>(&xs[r * 264 + w]) = v;
        }
    }
    __syncthreads();
    int r = tid >> 2, g = tid & 3;
    int n0 = g * 3;
    float a0r = 0.f, a0i = 0.f, a1r = 0.f, a1i = 0.f, a2r = 0.f, a2i = 0.f;
    const ST* xrow = &xs[r * 264];
    const float2* c0 = &ct[(n0 + 0) * 258];
    const float2* c1 = &ct[(n0 + 1) * 258];
    const float2* c2 = &ct[(n0 + 2) * 258];
#pragma unroll 8
    for (int wc = 0; wc < 256; wc += 4) {
        float x0, x1, x2, x3;
        if constexpr (BF) {
            ushort4 u = *reinterpret_cast<const ushort4*>(xrow + wc);
            x0 = bf2f(u.x); x1 = bf2f(u.y); x2 = bf2f(u.z); x3 = bf2f(u.w);
        } else {
            float4 f = *reinterpret_cast<const float4*>(xrow + wc);
            x0 = f.x; x1 = f.y; x2 = f.z; x3 = f.w;
        }
        float4 pa, pb;
        pa = *reinterpret_cast<const float4*>(c0 + wc);
        pb = *reinterpret_cast<const float4*>(c0 + wc + 2);
        a0r = fmaf(x0, pa.x, a0r); a0i = fmaf(x0, pa.y, a0i);
        a0r = fmaf(x1, pa.z, a0r); a0i = fmaf(x1, pa.w, a0i);
        a0r = fmaf(x2, pb.x, a0r); a0i = fmaf(x2, pb.y, a0i);
        a0r = fmaf(x3, pb.z, a0r); a0i = fmaf(x3, pb.w, a0i);
        pa = *reinterpret_cast<const float4*>(c1 + wc);
        pb = *reinterpret_cast<const float4*>(c1 + wc + 2);
        a1r = fmaf(x0, pa.x, a1r); a1i = fmaf(x0, pa.y, a1i);
        a1r = fmaf(x1, pa.z, a1r); a1i = fmaf(x1, pa.w, a1i);
        a1r = fmaf(x2, pb.x, a1r); a1i = fmaf(x2, pb.y, a1i);
        a1r = fmaf(x3, pb.z, a1r); a1i = fmaf(x3, pb.w, a1i);
        pa = *reinterpret_cast<const float4*>(c2 + wc);
        pb = *reinterpret_cast<const float4*>(c2 + wc + 2);
        a2r = fmaf(x0, pa.x, a2r); a2i = fmaf(x0, pa.y, a2i);
        a2r = fmaf(x1, pa.z, a2r); a2i = fmaf(x1, pa.w, a2i);
        a2r = fmaf(x2, pb.x, a2r); a2i = fmaf(x2, pb.y, a2i);
        a2r = fmaf(x3, pb.z, a2r); a2i = fmaf(x3, pb.w, a2i);
    }
    size_t bc = row0 >> 8;
    int hrow = (int)(row0 & 255) + r;
    float2* dst = Xw + (bc * 12) * 256 + hrow;
    dst[(size_t)(n0 + 0) * 256] = make_float2(a0r, a0i);
    dst[(size_t)(n0 + 1) * 256] = make_float2(a1r, a1i);
    dst[(size_t)(n0 + 2) * 256] = make_float2(a2r, a2i);
}

__global__ void k_rowdft(const float2* __restrict__ Xw, float2* __restrict__ F) {
    __shared__ float2 sm[12 * 257];
    int bc = blockIdx.x;
    const float2* src = Xw + (size_t)bc * 3072;
    for (int idx = threadIdx.x; idx < 3072; idx += 256) {
        int n = idx >> 8, hh = idx & 255;
        sm[n * 257 + hh] = src[idx];
    }
    __syncthreads();
    for (int j = threadIdx.x; j < 288; j += 256) {
        int n = j % 12, mm = j / 12;
        int meff = (mm < 12) ? mm : mm - 24;
        float s, c;
        __sincosf(-PI2 * (float)meff * (1.0f / 256.0f), &s, &c);
        float br = c, bi = s;
        float tr = 1.f, ti = 0.f, Fr = 0.f, Fi = 0.f;
        for (int hh = 0; hh < 256; hh++) {
            float2 xv = sm[n * 257 + hh];
            Fr = fmaf(xv.x, tr, Fr); Fr = fmaf(-xv.y, ti, Fr);
            Fi = fmaf(xv.x, ti, Fi); Fi = fmaf(xv.y, tr, Fi);
            float nr = tr * br - ti * bi;
            ti = tr * bi + ti * br;
            tr = nr;
        }
        F[(size_t)bc * 288 + j] = make_float2(Fr, Fi);
    }
}

__global__ void k_specmul(const float2* __restrict__ F,
                          const float* __restrict__ s1r, const float* __restrict__ s1i,
                          const float* __restrict__ s2r, const float* __restrict__ s2i,
                          float2* __restrict__ Y, int l) {
    __shared__ float2 wsh[4096];
    int mm = blockIdx.x / 12, n = blockIdx.x % 12;
    const float* wr; const float* wi; int m;
    if (mm < 12) { wr = s1r; wi = s1i; m = mm; }
    else         { wr = s2r; wi = s2i; m = mm - 12; }
    size_t base = (size_t)l * 589824 + (size_t)m * 12 + n;
    for (int idx = threadIdx.x; idx < 4096; idx += 256) {
        size_t a = base + (size_t)idx * 144;
        wsh[idx] = make_float2(wr[a], wi[a]);
    }
    __syncthreads();
    int o = threadIdx.x & 63, bq = threadIdx.x >> 6;
    for (int it = 0; it < 4; it++) {
        int b = bq * 4 + it;
        float Yr = 0.f, Yi = 0.f;
        const float2* Fb = F + (size_t)b * 64 * 288 + mm * 12 + n;
        for (int c = 0; c < 64; c++) {
            float2 fc = Fb[(size_t)c * 288];
            float2 wv = wsh[c * 64 + o];
            Yr = fmaf(fc.x, wv.x, Yr); Yr = fmaf(-fc.y, wv.y, Yr);
            Yi = fmaf(fc.x, wv.y, Yi); Yi = fmaf(fc.y, wv.x, Yi);
        }
        Y[((size_t)b * 64 + o) * 288 + mm * 12 + n] = make_float2(Yr, Yi);
    }
}

__global__ void k_expand(const float2* __restrict__ Y, float2* __restrict__ G) {
    int t = blockIdx.x * 256 + threadIdx.x;
    int hh = t & 255;
    int rem = t >> 8;
    int n = rem % 12, bo = rem / 12;
    const float2* Yb = Y + (size_t)bo * 288 + n;
    float s, c;
    __sincosf(PI2 * (float)hh * (1.0f / 256.0f), &s, &c);
    float br = c, bi = s;
    float tr = 1.f, ti = 0.f, Gr = 0.f, Gi = 0.f;
#pragma unroll
    for (int mm = 0; mm < 12; mm++) {
        float2 yv = Yb[mm * 12];
        Gr = fmaf(yv.x, tr, Gr); Gr = fmaf(-yv.y, ti, Gr);
        Gi = fmaf(yv.x, ti, Gi); Gi = fmaf(yv.y, tr, Gi);
        float nr = tr * br - ti * bi;
        ti = tr * bi + ti * br;
        tr = nr;
    }
    ti = -ti;
#pragma unroll
    for (int mm = 12; mm < 24; mm++) {
        float2 yv = Yb[mm * 12];
        Gr = fmaf(yv.x, tr, Gr); Gr = fmaf(-yv.y, ti, Gr);
        Gi = fmaf(yv.x, ti, Gi); Gi = fmaf(yv.y, tr, Gi);
        float nr = tr * br - ti * bi;
        ti = tr * bi + ti * br;
        tr = nr;
    }
    float sc = (n == 0 ? 1.0f : 2.0f) * (1.0f / 65536.0f);
    G[t] = make_float2(Gr * sc, Gi * sc);
}

template<bool BF>
__global__ __launch_bounds__(256) void k_update(
        typename HS<BF>::ST* __restrict__ h, const float2* __restrict__ G,
        const float* __restrict__ skw, const float* __restrict__ skb, int l) {
    __shared__ float hin[64 * 64];
    __shared__ float swT[64 * 68];
    __shared__ float2 Gs[64 * 12];
    __shared__ float2 ctab[12 * 64];
    int bx = blockIdx.x;
    int wt = bx & 3, hrow = (bx >> 2) & 255, b = bx >> 10;
    int w0 = wt * 64;
    int tid = threadIdx.x;
    size_t base4 = (size_t)b * 1048576 + (size_t)hrow * 64 + (w0 >> 2);
#pragma unroll
    for (int k = 0; k < 4; k++) {
        int idx = tid + k * 256;
        int c = idx >> 4, q = idx & 15;
        reinterpret_cast<float4*>(hin)[c * 16 + q] =
            HS<BF>::ld4(h, base4 + (size_t)c * 16384 + q);
    }
#pragma unroll
    for (int k = 0; k < 16; k++) {
        int idx = tid + k * 256;
        swT[(idx & 63) * 68 + (idx >> 6)] = skw[l * 4096 + idx];
    }
#pragma unroll
    for (int k = 0; k < 3; k++) {
        int idx = tid + k * 256;
        int o = idx / 12, n = idx % 12;
        Gs[idx] = G[(((size_t)b * 64 + o) * 12 + n) * 256 + hrow];
    }
#pragma unroll
    for (int k = 0; k < 3; k++) {
        int idx = tid + k * 256;
        int n = idx >> 6, wl = idx & 63;
        int r = (n * (w0 + wl)) & 255;
        float s, c;
        __sincosf(PI2 * (float)r * (1.0f / 256.0f), &s, &c);
        ctab[idx] = make_float2(c, s);
    }
    __syncthreads();
    int wq = tid & 15, oq = tid >> 4;
    float acc[4][4];
#pragma unroll
    for (int jo = 0; jo < 4; jo++) {
        float bias = skb[l * 64 + oq * 4 + jo];
#pragma unroll
        for (int jw = 0; jw < 4; jw++) acc[jo][jw] = bias;
    }
#pragma unroll
    for (int n = 0; n < 12; n++) {
        float2 g0 = Gs[(oq * 4 + 0) * 12 + n];
        float2 g1 = Gs[(oq * 4 + 1) * 12 + n];
        float2 g2 = Gs[(oq * 4 + 2) * 12 + n];
        float2 g3 = Gs[(oq * 4 + 3) * 12 + n];
#pragma unroll
        for (int jw = 0; jw < 4; jw++) {
            float2 cs = ctab[n * 64 + wq * 4 + jw];
            acc[0][jw] = fmaf(g0.x, cs.x, acc[0][jw]); acc[0][jw] = fmaf(-g0.y, cs.y, acc[0][jw]);
            acc[1][jw] = fmaf(g1.x, cs.x, acc[1][jw]); acc[1][jw] = fmaf(-g1.y, cs.y, acc[1][jw]);
            acc[2][jw] = fmaf(g2.x, cs.x, acc[2][jw]); acc[2][jw] = fmaf(-g2.y, cs.y, acc[2][jw]);
            acc[3][jw] = fmaf(g3.x, cs.x, acc[3][jw]); acc[3][jw] = fmaf(-g3.y, cs.y, acc[3][jw]);
        }
    }
    const float4* hin4 = reinterpret_cast<const float4*>(hin);
    const float4* swT4 = reinterpret_cast<const float4*>(swT);
#pragma unroll 4
    for (int c = 0; c < 64; c++) {
        float4 hv = hin4[c * 16 + wq];
        float4 wv = swT4[c * 17 + oq];
        acc[0][0] = fmaf(wv.x, hv.x, acc[0][0]); acc[0][1] = fmaf(wv.x, hv.y, acc[0][1]);
        acc[0][2] = fmaf(wv.x, hv.z, acc[0][2]); acc[0][3] = fmaf(wv.x, hv.w, acc[0][3]);
        acc[1][0] = fmaf(wv.y, hv.x, acc[1][0]); acc[1][1] = fmaf(wv.y, hv.y, acc[1][1]);
        acc[1][2] = fmaf(wv.y, hv.z, acc[1][2]); acc[1][3] = fmaf(wv.y, hv.w, acc[1][3]);
        acc[2][0] = fmaf(wv.z, hv.x, acc[2][0]); acc[2][1] = fmaf(wv.z, hv.y, acc[2][1]);
        acc[2][2] = fmaf(wv.z, hv.z, acc[2][2]); acc[2][3] = fmaf(wv.z, hv.w, acc[2][3]);
        acc[3][0] = fmaf(wv.w, hv.x, acc[3][0]); acc[3][1] = fmaf(wv.w, hv.y, acc[3][1]);
        acc[3][2] = fmaf(wv.w, hv.z, acc[3][2]); acc[3][3] = fmaf(wv.w, hv.w, acc[3][3]);
    }
#pragma unroll
    for (int jo = 0; jo < 4; jo++) {
        int o = oq * 4 + jo;
        float4 r;
        r.x = gelu_exact(acc[jo][0]); r.y = gelu_exact(acc[jo][1]);
        r.z = gelu_exact(acc[jo][2]); r.w = gelu_exact(acc[jo][3]);
        HS<BF>::st4(h, base4 + (size_t)o * 16384 + wq, r);
    }
}

template<bool BF>
__global__ void k_proj(const typename HS<BF>::ST* __restrict__ h, const float* __restrict__ pw,
                       const float* __restrict__ pb, float* __restrict__ out) {
    int i = blockIdx.x * 256 + threadIdx.x;
    int b = i >> 14, p4 = i & 16383;
    size_t hb = (size_t)b * 1048576 + p4;
    float4 acc = make_float4(0.f, 0.f, 0.f, 0.f);
#pragma unroll 8
    for (int c = 0; c < 64; c++) {
        float4 hv = HS<BF>::ld4(h, hb + (size_t)c * 16384);
        float wv = pw[c];
        acc.x = fmaf(hv.x, wv, acc.x); acc.y = fmaf(hv.y, wv, acc.y);
        acc.z = fmaf(hv.z, wv, acc.z); acc.w = fmaf(hv.w, wv, acc.w);
    }
    float bias = pb[0];
    acc.x += bias; acc.y += bias; acc.z += bias; acc.w += bias;
    reinterpret_cast<float4*>(out)[i] = acc;
}

// ============================ fused MFMA path (tier B) ======================
// G / Xw packed chunks (aliased buffer GXw, ushort): per (b,hrow) 3072 ushort:
//   [hi: 64 o x 24 k2][lo: 64 o x 24 k2], element (o, k2=2n+comp): o*24+n*2+comp
// Y (transposed): [b][n][o][mm] float2  (written by specmul2, read by expand3)
// Tg table (global ushort, 159,744 B): see R6 comment.
#define SKWHI 22528
#define SKWLO 38912
#define TW2US 55296
__global__ __launch_bounds__(256) void k_ttab(unsigned short* __restrict__ Tg,
                                              const float* __restrict__ skw) {
    int idx = blockIdx.x * 256 + threadIdx.x;     // 312*256 = 79872
    if (idx >= 79872) return;
    if (idx < 16384) {
        int q = idx & 8191;
        int w = q >> 5, b3 = (q >> 3) & 3;
        int k2 = ((b3 ^ (w & 3)) << 3) | (q & 7);
        float v = 0.f;
        if (k2 < 24) {
            int n = k2 >> 1, r = (n * w) & 255;
            float s, c;
            __sincosf(PI2 * (float)r * (1.0f / 256.0f), &s, &c);
            v = (k2 & 1) ? s : c;
        }
        if (idx < 8192) Tg[idx] = f2bf(v);
        else { unsigned short hi = f2bf(v); Tg[idx] = f2bf(v - bf2f(hi)); }
    } else if (idx < 22528) {
        int q = idx - 16384;
        int n2 = q >> 8, t = q & 255;
        int w = (((t >> 3) ^ (n2 & 7)) << 3) | (t & 7);
        int n = n2 >> 1, r = (n * w) & 255;
        float s, c;
        __sincosf(PI2 * (float)r * (1.0f / 256.0f), &s, &c);
        Tg[idx] = f2bf((n2 & 1) ? s : c);
    } else if (idx < 55296) {
        int q = idx - SKWHI;
        int lo = (q >= 16384);
        q &= 16383;
        float w = skw[q];
        unsigned short hi = f2bf(w);
        Tg[idx] = lo ? f2bf(w - bf2f(hi)) : hi;
    } else {
        int j = idx - TW2US;                      // 0..24575, one float each
        int pair = j >> 1, comp = j & 1;
        int mm = pair >> 8, hh = pair & 255;
        int meff = (mm < 12) ? mm : mm - 24;
        int r = (((-(meff * hh)) % 256) + 256) & 255;
        float s, c;
        __sincosf(PI2 * (float)r * (1.0f / 256.0f), &s, &c);
        reinterpret_cast<float*>(Tg + TW2US)[j] = comp ? s : c;
    }
}

// layer-0 Xw chunks via the rank-1 lift identity
__global__ __launch_bounds__(256) void k_xw0(const float* __restrict__ xg,
                                             const float* __restrict__ lw,
                                             const float* __restrict__ lb,
                                             unsigned short* __restrict__ Xwp) {
    __shared__ float xr[256];
    __shared__ float part[24][9];
    __shared__ float xh[24];
    int blk = blockIdx.x;                         // b*256 + hrow
    int tid = threadIdx.x;
    if (tid < 64)
        reinterpret_cast<float4*>(xr)[tid] =
            reinterpret_cast<const float4*>(xg + (size_t)blk * 256)[tid];
    __syncthreads();
    if (tid < 192) {
        int n2 = tid % 24, seg = tid / 24;
        int n = n2 >> 1, comp = n2 & 1;
        float acc = 0.f;
#pragma unroll 8
        for (int j = 0; j < 32; j++) {
            int w = seg * 32 + j;
            int r = (n * w) & 255;
            float s, c;
            __sincosf(PI2 * (float)r * (1.0f / 256.0f), &s, &c);
            acc = fmaf(xr[w], comp ? -s : c, acc);
        }
        part[n2][seg] = acc;
    }
    __syncthreads();
    if (tid < 24) {
        float a = 0.f;
#pragma unroll
        for (int s = 0; s < 8; s++) a += part[tid][s];
        xh[tid] = a;
    }
    __syncthreads();
    unsigned* dstw = reinterpret_cast<unsigned*>(Xwp + (size_t)blk * 3072);
#pragma unroll
    for (int q = 0; q < 3; q++) {
        int i = tid + q * 256;
        int c = i / 12, n = i % 12;
        float wr = lw[c];
        float re = fmaf(wr, xh[2 * n], (n == 0) ? lb[c] * 256.0f : 0.0f);
        float im = wr * xh[2 * n + 1];
        unsigned short hre = f2bf(re), him = f2bf(im);
        unsigned short lre = f2bf(re - bf2f(hre)), lim = f2bf(im - bf2f(him));
        dstw[i] = (unsigned)hre | ((unsigned)him << 16);
        dstw[768 + i] = (unsigned)lre | ((unsigned)lim << 16);
    }
}

// row DFT reading packed Xw chunks — b128 vectorized, 2 accumulator pairs
__global__ __launch_bounds__(256) void k_rowdft2t(const unsigned short* __restrict__ Xwp,
                                                  float2* __restrict__ F,
                                                  const float2* __restrict__ tw2) {
    __shared__ __align__(16) float2 sm[12 * 258];
    int bc = blockIdx.x;
    int b = bc >> 6, c = bc & 63;
    for (int idx = threadIdx.x; idx < 3072; idx += 256) {
        int hh = idx / 12, n = idx % 12;
        size_t base = ((size_t)(b * 256 + hh)) * 3072 + c * 24 + n * 2;
        unsigned hi = *reinterpret_cast<const unsigned*>(Xwp + base);
        unsigned lo = *reinterpret_cast<const unsigned*>(Xwp + base + 1536);
        float re = bf2f((unsigned short)(hi & 0xffff)) + bf2f((unsigned short)(lo & 0xffff));
        float im = bf2f((unsigned short)(hi >> 16)) + bf2f((unsigned short)(lo >> 16));
        sm[n * 258 + hh] = make_float2(re, im);
    }
    __syncthreads();
    for (int j = threadIdx.x; j < 288; j += 256) {
        int n = j % 12, mm = j / 12;
        const float4* twp = reinterpret_cast<const float4*>(tw2 + mm * 256);
        const float4* smp = reinterpret_cast<const float4*>(&sm[n * 258]);
        float Fr0 = 0.f, Fi0 = 0.f, Fr1 = 0.f, Fi1 = 0.f;
#pragma unroll 8
        for (int p = 0; p < 128; p++) {
            float4 xv = smp[p];                   // 2 complex samples
            float4 wv = twp[p];
            Fr0 = fmaf(xv.x, wv.x, Fr0); Fr0 = fmaf(-xv.y, wv.y, Fr0);
            Fi0 = fmaf(xv.x, wv.y, Fi0); Fi0 = fmaf(xv.y, wv.x, Fi0);
            Fr1 = fmaf(xv.z, wv.z, Fr1); Fr1 = fmaf(-xv.w, wv.w, Fr1);
            Fi1 = fmaf(xv.z, wv.w, Fi1); Fi1 = fmaf(xv.w, wv.z, Fi1);
        }
        F[(size_t)bc * 288 + j] = make_float2(Fr0 + Fr1, Fi0 + Fi1);
    }
}

// specmul, high-MLP version: 1024 threads, b folded into the thread grid.
// Writes Y TRANSPOSED: Yt[((b*12+n)*64+o)*24 + mm]  (mm contiguous for expand3)
__global__ __launch_bounds__(1024) void k_specmul2(const float2* __restrict__ F,
                          const float* __restrict__ s1r, const float* __restrict__ s1i,
                          const float* __restrict__ s2r, const float* __restrict__ s2i,
                          float2* __restrict__ Yt, int l) {
    __shared__ float2 wsh[4096];
    __shared__ float2 fsh[1024];
    int mm = blockIdx.x / 12, n = blockIdx.x % 12;
    const float* wr; const float* wi; int m;
    if (mm < 12) { wr = s1r; wi = s1i; m = mm; }
    else         { wr = s2r; wi = s2i; m = mm - 12; }
    size_t base = (size_t)l * 589824 + (size_t)m * 12 + n;
    int tid = threadIdx.x;
#pragma unroll
    for (int k = 0; k < 4; k++) {
        int idx = tid + k * 1024;                 // idx = c*64+o
        size_t a = base + (size_t)idx * 144;
        wsh[idx] = make_float2(wr[a], wi[a]);
    }
    fsh[tid] = F[(size_t)tid * 288 + mm * 12 + n];  // tid = b*64+c
    __syncthreads();
    int o = tid & 63, b = tid >> 6;
    const float2* fb = &fsh[b * 64];
    float Yr = 0.f, Yi = 0.f;
#pragma unroll 8
    for (int c = 0; c < 64; c++) {
        float2 fc = fb[c];
        float2 wv = wsh[c * 64 + o];
        Yr = fmaf(fc.x, wv.x, Yr); Yr = fmaf(-fc.y, wv.y, Yr);
        Yi = fmaf(fc.x, wv.y, Yi); Yi = fmaf(fc.y, wv.x, Yi);
    }
    Yt[(((size_t)b * 12 + n) * 64 + o) * 24 + mm] = make_float2(Yr, Yi);
}

// expand3: block = (b, 4 consecutive hh). Y[n][o][mm] contiguous in mm ->
// 6 b128 loads/output, held in regs across the 4 hh (16x fewer VMEM issues
// and 4x less L2 traffic than the old per-(b,hh) scalar version).
// Twiddles from tw2 table (conj): tw = (tw2.x, -tw2.y).
__global__ __launch_bounds__(256) void k_expand3(const float2* __restrict__ Yt,
                                                 unsigned short* __restrict__ Gpk,
                                                 const float2* __restrict__ tw2) {
    __shared__ float2 tw[4][24];
    int blk = blockIdx.x;                         // 1024 = b*64 + hh4
    int b = blk >> 6, hh0 = (blk & 63) * 4;
    int t = threadIdx.x;
    if (t < 96) {
        int hi = t / 24, mm = t % 24;
        float2 v = tw2[mm * 256 + hh0 + hi];
        tw[hi][mm] = make_float2(v.x, -v.y);
    }
    __syncthreads();
#pragma unroll
    for (int q = 0; q < 3; q++) {
        int j = t + q * 256;                      // 0..767
        int n = j >> 6, o = j & 63;
        const float4* Yp = reinterpret_cast<const float4*>(
            Yt + (((size_t)b * 12 + n) * 64 + o) * 24);
        float4 yv0 = Yp[0], yv1 = Yp[1], yv2 = Yp[2];
        float4 yv3 = Yp[3], yv4 = Yp[4], yv5 = Yp[5];
        float4 yv6 = Yp[6], yv7 = Yp[7], yv8 = Yp[8];
        float4 yv9 = Yp[9], yv10 = Yp[10], yv11 = Yp[11];
        float sc = (n == 0 ? 1.0f : 2.0f) * (1.0f / 65536.0f);
        int off = o * 24 + n * 2;
#pragma unroll
        for (int hi = 0; hi < 4; hi++) {
            float Gr = 0.f, Gi = 0.f;
            const float2* twh = tw[hi];
#define EXP_ACC(V, M0) \
            { float2 w0 = twh[M0], w1 = twh[M0 + 1]; \
              Gr = fmaf((V).x, w0.x, Gr); Gr = fmaf(-(V).y, w0.y, Gr); \
              Gi = fmaf((V).x, w0.y, Gi); Gi = fmaf((V).y, w0.x, Gi); \
              Gr = fmaf((V).z, w1.x, Gr); Gr = fmaf(-(V).w, w1.y, Gr); \
              Gi = fmaf((V).z, w1.y, Gi); Gi = fmaf((V).w, w1.x, Gi); }
            EXP_ACC(yv0, 0)  EXP_ACC(yv1, 2)  EXP_ACC(yv2, 4)
            EXP_ACC(yv3, 6)  EXP_ACC(yv4, 8)  EXP_ACC(yv5, 10)
            EXP_ACC(yv6, 12) EXP_ACC(yv7, 14) EXP_ACC(yv8, 16)
            EXP_ACC(yv9, 18) EXP_ACC(yv10, 20) EXP_ACC(yv11, 22)
#undef EXP_ACC
            float gr = Gr * sc, gi = -Gi * sc;
            unsigned short hre = f2bf(gr), him = f2bf(gi);
            unsigned short lre = f2bf(gr - bf2f(hre)), lim = f2bf(gi - bf2f(him));
            unsigned short* Gb = Gpk + ((size_t)(b * 256 + hh0 + hi)) * 3072;
            *reinterpret_cast<unsigned*>(Gb + off) = (unsigned)hre | ((unsigned)him << 16);
            *reinterpret_cast<unsigned*>(Gb + 1536 + off) = (unsigned)lre | ((unsigned)lim << 16);
        }
    }
}

// fused: transposed GEMM (D=[w][o]) + gelu + {h write | proj} + {colDFT | -}.
// hnew lives IN the hT region as XOR-swizzled [64][256]:
//   elem (o,w) at o*256 + (w ^ ((o&7)<<3))   -> LDS = 32 KB, 5 blocks/CU.
// launch_bounds min-waves = 4 (NOT 5): R11 showed 5 strangles VGPR -> spill.
// Staging uses c-quad b64 writes: 16 banks/half-wave = 2-way (free).
template<bool FIRST, bool LAST>
__global__ __launch_bounds__(256, 4) void k_fused3(
        unsigned short* hg, const float* __restrict__ xg,
        const float* __restrict__ lw, const float* __restrict__ lb,
        unsigned short* GXw, const float* __restrict__ skb,
        const float* __restrict__ pw, const float* __restrict__ pb,
        float* __restrict__ outg, const unsigned short* __restrict__ Tg, int l) {
    __shared__ __align__(16) unsigned short lds[16384];   // hT | hnew (swizzled)
    int tid = threadIdx.x, lane = tid & 63, wid = tid >> 6;
    int lr = lane & 15, lg = lane >> 4;
    int bx = blockIdx.x;
    int hrow = bx & 255, b = bx >> 8;

    // ---- stage hT[w][c] (swizzled) ----
    if constexpr (FIRST) {
#pragma unroll
        for (int k = 0; k < 4; k++) {
            int pidx = tid + k * 256;
            int cp = pidx >> 5, w0 = (pidx & 31) * 8;
            int c0 = cp * 2;
            float wa = lw[c0], ba = lb[c0];
            float wb = lw[c0 + 1], bb = lb[c0 + 1];
            float4 xv0 = *reinterpret_cast<const float4*>(xg + (size_t)bx * 256 + w0);
            float4 xv1 = *reinterpret_cast<const float4*>(xg + (size_t)bx * 256 + w0 + 4);
            float xv[8] = {xv0.x, xv0.y, xv0.z, xv0.w, xv1.x, xv1.y, xv1.z, xv1.w};
            int sl = (c0 >> 3) & 7, cl = c0 & 7;
#pragma unroll
            for (int j = 0; j < 8; j++) {
                int w = w0 + j;
                float h0 = fmaf(xv[j], wa, ba);
                float h1 = fmaf(xv[j], wb, bb);
                int Xws = (w & 7) ^ ((w >> 3) & 7);
                *reinterpret_cast<unsigned*>(&lds[w * 64 + (((sl ^ Xws) & 7) << 3) + cl]) =
                    cvtpk_bf16(h0, h1);
            }
        }
    } else {
        // c-quad staging: 512 items = 16 quads x 32 w-chunks; b64 LDS writes
#pragma unroll
        for (int k = 0; k < 2; k++) {
            int item = tid + k * 256;
            int q = item >> 5, w0 = (item & 31) * 8;
            int c0 = q * 4;
            const unsigned short* s0 = hg + ((size_t)(b * 64 + c0) * 256 + hrow) * 256 + w0;
            uint4 v0 = *reinterpret_cast<const uint4*>(s0);
            uint4 v1 = *reinterpret_cast<const uint4*>(s0 + 65536);
            uint4 v2 = *reinterpret_cast<const uint4*>(s0 + 131072);
            uint4 v3 = *reinterpret_cast<const uint4*>(s0 + 196608);
            unsigned a01[8], a23[8];
            a01[0] = perm_lo(v0.x, v1.x); a01[1] = perm_hi(v0.x, v1.x);
            a01[2] = perm_lo(v0.y, v1.y); a01[3] = perm_hi(v0.y, v1.y);
            a01[4] = perm_lo(v0.z, v1.z); a01[5] = perm_hi(v0.z, v1.z);
            a01[6] = perm_lo(v0.w, v1.w); a01[7] = perm_hi(v0.w, v1.w);
            a23[0] = perm_lo(v2.x, v3.x); a23[1] = perm_hi(v2.x, v3.x);
            a23[2] = perm_lo(v2.y, v3.y); a23[3] = perm_hi(v2.y, v3.y);
            a23[4] = perm_lo(v2.z, v3.z); a23[5] = perm_hi(v2.z, v3.z);
            a23[6] = perm_lo(v2.w, v3.w); a23[7] = perm_hi(v2.w, v3.w);
            int sl = (c0 >> 3) & 7, cl = c0 & 7;   // cl in {0,4}
#pragma unroll
            for (int j = 0; j < 8; j++) {
                int w = w0 + j;
                int Xws = (w & 7) ^ ((w >> 3) & 7);
                u32x2 pk;
                pk[0] = a01[j]; pk[1] = a23[j];
                *reinterpret_cast<u32x2*>(&lds[w * 64 + (((sl ^ Xws) & 7) << 3) + cl]) = pk;
            }
        }
    }
    // ---- B fragments: skw hi/lo + G hi/lo, col o = wid*16+lr ----
    int oA = wid * 16 + lr;
    bf16x8 bs_h[2], bs_l[2];
#pragma unroll
    for (int ks = 0; ks < 2; ks++) {
        int off = l * 4096 + oA * 64 + ks * 32 + lg * 8;
        bs_h[ks] = __builtin_bit_cast(bf16x8,
            *reinterpret_cast<const u32x4*>(Tg + SKWHI + off));
        bs_l[ks] = __builtin_bit_cast(bf16x8,
            *reinterpret_cast<const u32x4*>(Tg + SKWLO + off));
    }
    int lgc = (lg < 3) ? lg : 2;
    size_t gbase = ((size_t)(b * 256 + hrow)) * 3072 + (size_t)oA * 24 + lgc * 8;
    u32x4 ghv = *reinterpret_cast<const u32x4*>(GXw + gbase);
    u32x4 glv = *reinterpret_cast<const u32x4*>(GXw + gbase + 1536);
    if (lg == 3) { ghv = (u32x4){0, 0, 0, 0}; glv = (u32x4){0, 0, 0, 0}; }
    bf16x8 bg_h = __builtin_bit_cast(bf16x8, ghv);
    bf16x8 bg_l = __builtin_bit_cast(bf16x8, glv);
    float bias_o = skb[l * 64 + oA];
    f32x4 binit = {bias_o, bias_o, bias_o, bias_o};

    __syncthreads();

    // ---- main GEMM (operand-swapped): acc[wt] = D'[w][o] tile ----
    f32x4 acc[16];
#pragma unroll
    for (int wt = 0; wt < 16; wt++) acc[wt] = binit;
    __builtin_amdgcn_s_setprio(1);
#pragma unroll
    for (int wt = 0; wt < 16; wt++) {
        int w = wt * 16 + lr;
        int Xws = (w & 7) ^ ((w >> 3) & 7);
        int i0 = w * 64 + (((lg ^ Xws) & 7) << 3);
        int i1 = w * 64 + ((((4 + lg) ^ Xws) & 7) << 3);
        int it = w * 32 + (((lg ^ (w & 3)) & 3) << 3);
        bf16x8 A0 = __builtin_bit_cast(bf16x8, *reinterpret_cast<const u32x4*>(&lds[i0]));
        bf16x8 A1 = __builtin_bit_cast(bf16x8, *reinterpret_cast<const u32x4*>(&lds[i1]));
        bf16x8 Th = __builtin_bit_cast(bf16x8, *reinterpret_cast<const u32x4*>(Tg + it));
        bf16x8 Tl = __builtin_bit_cast(bf16x8, *reinterpret_cast<const u32x4*>(Tg + 8192 + it));
        acc[wt] = __builtin_amdgcn_mfma_f32_16x16x32_bf16(A0, bs_h[0], acc[wt], 0, 0, 0);
        acc[wt] = __builtin_amdgcn_mfma_f32_16x16x32_bf16(A0, bs_l[0], acc[wt], 0, 0, 0);
        acc[wt] = __builtin_amdgcn_mfma_f32_16x16x32_bf16(A1, bs_h[1], acc[wt], 0, 0, 0);
        acc[wt] = __builtin_amdgcn_mfma_f32_16x16x32_bf16(A1, bs_l[1], acc[wt], 0, 0, 0);
        acc[wt] = __builtin_amdgcn_mfma_f32_16x16x32_bf16(Th, bg_h, acc[wt], 0, 0, 0);
        acc[wt] = __builtin_amdgcn_mfma_f32_16x16x32_bf16(Tl, bg_h, acc[wt], 0, 0, 0);
        acc[wt] = __builtin_amdgcn_mfma_f32_16x16x32_bf16(Th, bg_l, acc[wt], 0, 0, 0);
    }
    __builtin_amdgcn_s_setprio(0);
    __syncthreads();                              // hT dead

    // ---- epilogue: gelu + cvt_pk -> swizzled hnew (b64 writes) ----
    int wD = lg * 4;
    int osw = (oA & 7) << 3;
#pragma unroll
    for (int wt = 0; wt < 16; wt++) {
        float v0 = gelu_fast(acc[wt][0]);
        float v1 = gelu_fast(acc[wt][1]);
        float v2 = gelu_fast(acc[wt][2]);
        float v3 = gelu_fast(acc[wt][3]);
        u32x2 pk;
        pk[0] = cvtpk_bf16(v0, v1);
        pk[1] = cvtpk_bf16(v2, v3);
        *reinterpret_cast<u32x2*>(&lds[oA * 256 + ((wt * 16 + wD) ^ osw)]) = pk;
    }
    __syncthreads();

    if constexpr (LAST) {
        // ---- proj-reduce: out[b,hrow,w] = pb + sum_o pw[o]*hnew[o][w] ----
        float accp = pb[0];
#pragma unroll 8
        for (int o = 0; o < 64; o++)
            accp = fmaf(pw[o], bf2f(lds[o * 256 + (tid ^ ((o & 7) << 3))]), accp);
        outg[(size_t)bx * 256 + tid] = accp;
        return;
    }

    // ---- copy hnew -> global (coalesced; swizzled b128 LDS reads) ----
#pragma unroll
    for (int k = 0; k < 8; k++) {
        int chi = k * 256 + tid;
        int o = chi >> 5, wq = (chi & 31) * 8;
        u32x4 v = *reinterpret_cast<const u32x4*>(&lds[o * 256 + (wq ^ ((o & 7) << 3))]);
        *reinterpret_cast<u32x4*>(hg + ((size_t)(b * 64 + o) * 256 + hrow) * 256 + wq) = v;
    }
    // ---- fused column-DFT for next layer ----
    f32x4 acc2[2];
    acc2[0] = (f32x4){0.f, 0.f, 0.f, 0.f};
    acc2[1] = (f32x4){0.f, 0.f, 0.f, 0.f};
    int oa = wid * 16 + lr;
    int oasw = (oa & 7) << 3;
#pragma unroll
    for (int sg = 0; sg < 8; sg++) {
        int wb = 4 * sg + lg;
        bf16x8 Af = __builtin_bit_cast(bf16x8,
            *reinterpret_cast<const u32x4*>(&lds[oa * 256 + ((wb * 8) ^ oasw)]));
#pragma unroll
        for (int nt = 0; nt < 2; nt++) {
            int n2 = nt * 16 + lr;
            int n2r = (n2 < 24) ? n2 : 23;        // cols >=24 discarded
            bf16x8 Bf = __builtin_bit_cast(bf16x8, *reinterpret_cast<const u32x4*>(
                Tg + 16384 + n2r * 256 + ((wb ^ (n2r & 7)) << 3)));
            acc2[nt] = __builtin_amdgcn_mfma_f32_16x16x32_bf16(Af, Bf, acc2[nt], 0, 0, 0);
        }
    }
    __syncthreads();                              // hnew LDS dead
    // ---- pack Xw (bf16 hi/lo) into LDS chunk, then coalesced copy out ----
    int oD = wid * 16 + lg * 4;
#pragma unroll
    for (int nt = 0; nt < 2; nt++) {
        int n2 = nt * 16 + lr;
        if (n2 < 24) {
            float sgn = (n2 & 1) ? -1.f : 1.f;
#pragma unroll
            for (int r = 0; r < 4; r++) {
                float v = sgn * acc2[nt][r];
                unsigned short hv = f2bf(v);
                unsigned short lv = f2bf(v - bf2f(hv));
                int o = oD + r;
                lds[o * 24 + n2] = hv;
                lds[1536 + o * 24 + n2] = lv;
            }
        }
    }
    __syncthreads();
    unsigned* dstw = reinterpret_cast<unsigned*>(GXw + ((size_t)(b * 256 + hrow)) * 3072);
    const unsigned* srcw = reinterpret_cast<const unsigned*>(lds);
#pragma unroll
    for (int q = 0; q < 3; q++) {
        int i = tid + q * 256;                    // 768 u32
        dstw[i] = srcw[i];
    }
}

// ============================ dispatch ======================================

template<bool BF>
static void run_pipeline_old(void* const* d_in, void* d_out, void* d_ws, hipStream_t stream) {
    const float* x   = (const float*)d_in[0];
    const float* lw  = (const float*)d_in[1];
    const float* lb  = (const float*)d_in[2];
    const float* s1r = (const float*)d_in[3];
    const float* s1i = (const float*)d_in[4];
    const float* s2r = (const float*)d_in[5];
    const float* s2i = (const float*)d_in[6];
    const float* skw = (const float*)d_in[7];
    const float* skb = (const float*)d_in[8];
    const float* pw  = (const float*)d_in[9];
    const float* pb  = (const float*)d_in[10];
    float* out = (float*)d_out;
    char* ws = (char*)d_ws;
    using ST = typename HS<BF>::ST;
    size_t hbytes = 67108864ull * sizeof(ST);
    ST*     hbuf = (ST*)ws;
    float2* XwG  = (float2*)(ws + hbytes);
    float2* F    = (float2*)(ws + hbytes + 25165824ull);
    float2* Y    = (float2*)(ws + hbytes + 25165824ull + 2359296ull);
    k_lift<BF><<<65536, 256, 0, stream>>>(x, lw, lb, hbuf);
    for (int l = 0; l < 4; l++) {
        k_coldft<BF><<<4096, 256, 0, stream>>>(hbuf, XwG);
        k_rowdft <<<1024,  256, 0, stream>>>(XwG, F);
        k_specmul<<<288,   256, 0, stream>>>(F, s1r, s1i, s2r, s2i, Y, l);
        k_expand <<<12288, 256, 0, stream>>>(Y, XwG);
        k_update<BF><<<16384, 256, 0, stream>>>(hbuf, XwG, skw, skb, l);
    }
    k_proj<BF><<<1024, 256, 0, stream>>>(hbuf, pw, pb, out);
}

static void run_pipeline_fused(void* const* d_in, void* d_out, void* d_ws, hipStream_t stream) {
    const float* x   = (const float*)d_in[0];
    const float* lw  = (const float*)d_in[1];
    const float* lb  = (const float*)d_in[2];
    const float* s1r = (const float*)d_in[3];
    const float* s1i = (const float*)d_in[4];
    const float* s2r = (const float*)d_in[5];
    const float* s2i = (const float*)d_in[6];
    const float* skw = (const float*)d_in[7];
    const float* skb = (const float*)d_in[8];
    const float* pw  = (const float*)d_in[9];
    const float* pb  = (const float*)d_in[10];
    float* out = (float*)d_out;
    char* ws = (char*)d_ws;
    unsigned short* hbuf = (unsigned short*)ws;
    unsigned short* XwG  = (unsigned short*)(ws + 134217728ull);
    float2* F   = (float2*)(ws + 134217728ull + 25165824ull);
    float2* Y   = (float2*)(ws + 134217728ull + 25165824ull + 2359296ull);
    unsigned short* Tg = (unsigned short*)(ws + 164102144ull);
    const float2* tw2 = (const float2*)((char*)Tg + 110592);

    k_ttab<<<312, 256, 0, stream>>>(Tg, skw);
    k_xw0<<<4096, 256, 0, stream>>>(x, lw, lb, XwG);
    for (int l = 0; l < 4; l++) {
        k_rowdft2t<<<1024, 256, 0, stream>>>(XwG, F, tw2);
        k_specmul2<<<288, 1024, 0, stream>>>(F, s1r, s1i, s2r, s2i, Y, l);
        k_expand3<<<1024, 256, 0, stream>>>(Y, XwG, tw2);
        if (l == 0)
            k_fused3<true, false><<<4096, 256, 0, stream>>>(hbuf, x, lw, lb, XwG, skb, pw, pb, out, Tg, l);
        else if (l == 3)
            k_fused3<false, true><<<4096, 256, 0, stream>>>(hbuf, x, lw, lb, XwG, skb, pw, pb, out, Tg, l);
        else
            k_fused3<false, false><<<4096, 256, 0, stream>>>(hbuf, x, lw, lb, XwG, skb, pw, pb, out, Tg, l);
    }
}

extern "C" void kernel_launch(void* const* d_in, const int* in_sizes, int n_in,
                              void* d_out, int out_size, void* d_ws, size_t ws_size,
                              hipStream_t stream) {
    // fused tier: 164,102,144 (bf16 h + XwG + F + Y) + 159,744 (Tg) = 164,261,888
    if (ws_size >= 164261888ull) {
        run_pipeline_fused(d_in, d_out, d_ws, stream);
    } else {
        run_pipeline_old<true>(d_in, d_out, d_ws, stream);
    }
}